// Round 15
// baseline (281.970 us; speedup 1.0000x reference)
//
#include <hip/hip_runtime.h>

#define B_N 4
#define S_LEN 4096
#define D_DIM 256
#define BS_TOT (B_N * S_LEN)
#define BSD_TOT ((size_t)BS_TOT * D_DIM)

typedef __attribute__((ext_vector_type(8))) short short8;
typedef __attribute__((ext_vector_type(4))) short short4_;
typedef __attribute__((ext_vector_type(4))) unsigned short ushort4_;
typedef __attribute__((ext_vector_type(4))) float f32x4;
typedef __attribute__((ext_vector_type(4))) int int4_;

static __device__ __forceinline__ unsigned short f2bf(float f) {
  unsigned u = __builtin_bit_cast(unsigned, f);
  u += 0x7fffu + ((u >> 16) & 1u);
  return (unsigned short)(u >> 16);
}
static __device__ __forceinline__ float bf2f(unsigned short h) {
  unsigned u = ((unsigned)h) << 16;
  return __builtin_bit_cast(float, u);
}

#if __has_builtin(__builtin_amdgcn_mfma_f32_16x16x16bf16_1k)
#define MFMA16(a, b, c) __builtin_amdgcn_mfma_f32_16x16x16bf16_1k((a), (b), (c), 0, 0, 0)
#else
static __device__ __forceinline__ f32x4 mfma16_asm(short4_ a, short4_ b, f32x4 c) {
  asm volatile("v_mfma_f32_16x16x16_bf16 %0, %1, %2, %0" : "+v"(c) : "v"(a), "v"(b));
  return c;
}
#define MFMA16(a, b, c) mfma16_asm((a), (b), (c))
#endif

// ---------------- Projection: Out[m][n] = sum_k X[m][k] * W[n][k]  (bf16 out) ----------------
__global__ __launch_bounds__(256, 2)
void proj_kernel(const float* __restrict__ X0, const float* __restrict__ X1,
                 const float* __restrict__ X2,
                 const float* __restrict__ W0, const float* __restrict__ W1,
                 const float* __restrict__ W2,
                 unsigned short* __restrict__ O0, unsigned short* __restrict__ O1,
                 unsigned short* __restrict__ O2) {
  __shared__ __align__(16) unsigned char sA[16384];
  __shared__ __align__(16) unsigned char sB[16384];

  const int z = (int)blockIdx.z;
  const float* X = (z == 0) ? X0 : (z == 1) ? X1 : X2;
  const float* W = (z == 0) ? W0 : (z == 1) ? W1 : W2;
  unsigned short* O = (z == 0) ? O0 : (z == 1) ? O1 : O2;
  const float mult = (z == 0) ? 0.0625f : 1.0f;  // fold 1/sqrt(D) into Q

  const int t = (int)threadIdx.x;
  const int l = t & 63, w = t >> 6;
  const int lm = l & 15, g = l >> 4;
  const int wr = w >> 1, wc = w & 1;
  const int mb = (int)blockIdx.x * 128;
  const int nb = (int)blockIdx.y * 128;

  f32x4 acc[4][4];
#pragma unroll
  for (int i = 0; i < 4; ++i)
#pragma unroll
    for (int j = 0; j < 4; ++j) acc[i][j] = (f32x4){0.f, 0.f, 0.f, 0.f};

  for (int ks = 0; ks < 4; ++ks) {
    const int k0 = ks * 64;
#pragma unroll
    for (int i = 0; i < 4; ++i) {
      const int c = t + i * 256;
      const int row = c >> 3;
      const int kc = (c & 7) * 8;
      const float* xp = X + (size_t)(mb + row) * D_DIM + k0 + kc;
      const float* wp = W + (size_t)(nb + row) * D_DIM + k0 + kc;
      f32x4 x0 = *(const f32x4*)xp;
      f32x4 x1 = *(const f32x4*)(xp + 4);
      f32x4 w0 = *(const f32x4*)wp;
      f32x4 w1 = *(const f32x4*)(wp + 4);
      short8 xa, wa;
#pragma unroll
      for (int j = 0; j < 4; ++j) {
        xa[j] = (short)f2bf(x0[j]);
        xa[j + 4] = (short)f2bf(x1[j]);
        wa[j] = (short)f2bf(w0[j]);
        wa[j + 4] = (short)f2bf(w1[j]);
      }
      const int off = row * 128 + ((kc * 2) ^ ((row & 7) << 4));
      *(short8*)&sA[off] = xa;
      *(short8*)&sB[off] = wa;
    }
    __syncthreads();
#pragma unroll
    for (int kk = 0; kk < 2; ++kk) {
      short8 af[4], bg[4];
#pragma unroll
      for (int mi = 0; mi < 4; ++mi) {
        const int row = wr * 64 + mi * 16 + lm;
        af[mi] = *(const short8*)&sA[row * 128 + (((kk * 32 + g * 8) * 2) ^ ((row & 7) << 4))];
      }
#pragma unroll
      for (int ni = 0; ni < 4; ++ni) {
        const int row = wc * 64 + ni * 16 + lm;
        bg[ni] = *(const short8*)&sB[row * 128 + (((kk * 32 + g * 8) * 2) ^ ((row & 7) << 4))];
      }
#pragma unroll
      for (int mi = 0; mi < 4; ++mi)
#pragma unroll
        for (int ni = 0; ni < 4; ++ni)
          acc[mi][ni] = __builtin_amdgcn_mfma_f32_16x16x32_bf16(af[mi], bg[ni], acc[mi][ni], 0, 0, 0);
    }
    __syncthreads();
  }

#pragma unroll
  for (int mi = 0; mi < 4; ++mi)
#pragma unroll
    for (int ni = 0; ni < 4; ++ni)
#pragma unroll
      for (int r = 0; r < 4; ++r) {
        const int mg = mb + wr * 64 + mi * 16 + g * 4 + r;
        const int ng = nb + wc * 64 + ni * 16 + lm;
        O[(size_t)mg * D_DIM + ng] = f2bf(acc[mi][ni][r] * mult);
      }
}

// ---------------- Per-tile mask flags: flags[b*64+tt] = all 64 mask vals nonzero ----------------
__global__ __launch_bounds__(64)
void mask_flags_kernel(const int* __restrict__ amask, int* __restrict__ flags) {
  const int idx = (int)blockIdx.x * 64 + (int)threadIdx.x;  // b*64 + tt
  const int4_* p = (const int4_*)(amask + (size_t)idx * 64);
  int all1 = 1;
#pragma unroll
  for (int i = 0; i < 16; ++i) {
    int4_ v = p[i];
    all1 &= (v[0] != 0) & (v[1] != 0) & (v[2] != 0) & (v[3] != 0);
  }
  flags[idx] = all1;
}

// ---------------- Flash attention: QBLK=128, chunk-pair, split-4, XCD-local, fused combine ----------------
// V^T LDS row layout: within each 128B d-row, key k = s*16+g*4+r lives at byte g*32 + s*8 + r*2,
// XOR-swizzled at 16B granule by ((d^(d>>4))&14)<<3. PV reads 2x b128 per (dt).
// Last split to finish a chunk (device-scope atomic ticket) combines the 4 partials into Out.
__global__ __launch_bounds__(512, 2)
void attn_split4_kernel(const unsigned short* __restrict__ Qb,
                        const unsigned short* __restrict__ Kb,
                        const unsigned short* __restrict__ Vb,
                        const int* __restrict__ amask,
                        const int* __restrict__ tflags,
                        unsigned short* __restrict__ Pall,  // 4 bf16 partials [h][B*S][D]
                        float* __restrict__ stats,          // m[4][B*S], l[4][B*S]
                        int* __restrict__ cnt,              // [B_N*32] tickets (zeroed per launch)
                        float* __restrict__ Out)
{
  // per buffer: K at [0,32768), V^T at [32768,65536)
  __shared__ __align__(16) unsigned char sBuf[2][65536];
  __shared__ int doComb;

  const int t = (int)threadIdx.x;
  const int l = t & 63;
  const int w = t >> 6;  // 0..7
  const int lm = l & 15;
  const int g = l >> 4;

  const int lin = (int)blockIdx.x;          // 0..255
  const int xcd = lin & 7;
  const int jslot = lin >> 3;               // 0..31
  const int b = xcd >> 1;                   // batch pinned to an XCD pair
  const int slot = (xcd & 1) * 32 + jslot;  // 0..63
  const int pp = slot >> 2;                 // pair index 0..15
  const int h = slot & 3;                   // split 0..3
  const size_t bS = (size_t)b * S_LEN;

  int4_ kreg[4], vreg[4];
  const int crow = t >> 5;        // 0..15: this thread owns key-rows crow*4 .. crow*4+3
  const int cd8 = (t & 31) << 3;  // d chunk start
  const int vko = (crow & 3) * 32 + (crow >> 2) * 8;  // [g][s] byte offset of this thread's 4 keys

#define LOAD_TILE(T0)                                                              \
  do {                                                                             \
    const size_t kb_ = bS + (size_t)((T0)*64);                                     \
    _Pragma("unroll") for (int i_ = 0; i_ < 4; ++i_) {                             \
      kreg[i_] = *(const int4_*)(Kb + (kb_ + crow * 4 + i_) * D_DIM + cd8);        \
      vreg[i_] = *(const int4_*)(Vb + (kb_ + crow * 4 + i_) * D_DIM + cd8);        \
    }                                                                              \
  } while (0)

#define STORE_TILE(BUF)                                                            \
  do {                                                                             \
    unsigned char* bK_ = (BUF);                                                    \
    unsigned char* bV_ = (BUF) + 32768;                                            \
    _Pragma("unroll") for (int i_ = 0; i_ < 4; ++i_) {                             \
      const int row_ = crow * 4 + i_;                                              \
      *(int4_*)&bK_[row_ * 512 + ((cd8 * 2) ^ ((row_ & 7) << 4))] = kreg[i_];      \
    }                                                                              \
    const unsigned short* v0_ = (const unsigned short*)&vreg[0];                   \
    const unsigned short* v1_ = (const unsigned short*)&vreg[1];                   \
    const unsigned short* v2_ = (const unsigned short*)&vreg[2];                   \
    const unsigned short* v3_ = (const unsigned short*)&vreg[3];                   \
    _Pragma("unroll") for (int jj_ = 0; jj_ < 8; ++jj_) {                          \
      const int d_ = cd8 + jj_;                                                    \
      const int sw_ = ((d_ ^ (d_ >> 4)) & 14) << 3;                                \
      short4_ pv_;                                                                 \
      pv_[0] = (short)v0_[jj_]; pv_[1] = (short)v1_[jj_];                          \
      pv_[2] = (short)v2_[jj_]; pv_[3] = (short)v3_[jj_];                          \
      *(short4_*)&bV_[d_ * 128 + (vko ^ sw_)] = pv_;                               \
    }                                                                              \
  } while (0)

  for (int ci = 0; ci < 2; ++ci) {
    const int qc = ci ? (31 - pp) : pp;
    const int last = 2 * qc + 1;
    const int qrow0 = qc * 128;
    const int q_g = qrow0 + w * 16 + lm;

    // Q fragments (B-operand of swapped QK^T): q = lm, k-chunk = ch*32 + g*8 + j
    short8 qf[8];
    {
      const unsigned short* qp = Qb + (bS + (size_t)(qrow0 + w * 16 + lm)) * D_DIM + g * 8;
#pragma unroll
      for (int ch = 0; ch < 8; ++ch) qf[ch] = *(const short8*)(qp + ch * 32);
    }

    f32x4 o[16];
#pragma unroll
    for (int dt = 0; dt < 16; ++dt) o[dt] = (f32x4){0.f, 0.f, 0.f, 0.f};
    float mrun = -1e30f, lrun = 0.f;

    // prologue: stage tile h into buf0; prefetch tile h+4 into regs
    if (h <= last) {
      LOAD_TILE(h);
      STORE_TILE(sBuf[0]);
      if (h + 4 <= last) LOAD_TILE(h + 4);
    }
    __syncthreads();

    int p = 0;
    for (int tt = h; tt <= last; tt += 4) {
      const int k0 = tt * 64;
      const unsigned char* bK = sBuf[p];
      const unsigned char* bV = sBuf[p] + 32768;

      // stage NEXT tile from regs, then issue loads for the one after (land during compute)
      if (tt + 4 <= last) {
        STORE_TILE(sBuf[p ^ 1]);
        if (tt + 8 <= last) LOAD_TILE(tt + 8);
      }

      // ---- QK^T (S^T = K * Q^T): C col = q (lm), C row = key-in-16 (g*4+r) ----
      f32x4 sacc[4];
#pragma unroll
      for (int s = 0; s < 4; ++s) sacc[s] = (f32x4){0.f, 0.f, 0.f, 0.f};
      __builtin_amdgcn_s_setprio(1);
#pragma unroll
      for (int ch = 0; ch < 8; ++ch) {
#pragma unroll
        for (int s = 0; s < 4; ++s) {
          const int key = s * 16 + lm;
          const int off = key * 512 + (((ch * 32 + g * 8) * 2) ^ ((key & 7) << 4));
          short8 kf = *(const short8*)&bK[off];
          sacc[s] = __builtin_amdgcn_mfma_f32_16x16x32_bf16(kf, qf[ch], sacc[s], 0, 0, 0);
        }
      }
      __builtin_amdgcn_s_setprio(0);

      // ---- online softmax (stats per q = lm, replicated across 4 lane groups) ----
      float sv[4][4];
      float tmax = -1e30f;
      const bool fastm = tflags[b * 64 + tt] && (k0 + 63 <= qrow0 + w * 16);
      if (fastm) {
#pragma unroll
        for (int s = 0; s < 4; ++s)
#pragma unroll
          for (int r = 0; r < 4; ++r) {
            sv[s][r] = sacc[s][r];
            tmax = fmaxf(tmax, sacc[s][r]);
          }
      } else {
#pragma unroll
        for (int s = 0; s < 4; ++s) {
          const int4_ mw = *(const int4_*)(amask + bS + k0 + s * 16 + g * 4);
#pragma unroll
          for (int r = 0; r < 4; ++r) {
            const int key_g = k0 + s * 16 + g * 4 + r;
            const bool ok = (key_g <= q_g) && (mw[r] != 0);
            const float x = ok ? sacc[s][r] : -1e30f;
            sv[s][r] = x;
            tmax = fmaxf(tmax, x);
          }
        }
      }
      tmax = fmaxf(tmax, __shfl_xor(tmax, 16));
      tmax = fmaxf(tmax, __shfl_xor(tmax, 32));

      // defer-rescale: exact skip when no row's max grew (corr == 1 for all lanes)
      if (__ballot(tmax > mrun)) {
        const float mnew = fmaxf(mrun, tmax);
        const float corr = __builtin_amdgcn_exp2f((mrun - mnew) * 1.44269504f);
        mrun = mnew;
        lrun *= corr;
        float cr[4];
#pragma unroll
        for (int r = 0; r < 4; ++r) cr[r] = __shfl(corr, g * 4 + r);
#pragma unroll
        for (int dt = 0; dt < 16; ++dt)
#pragma unroll
          for (int r = 0; r < 4; ++r) o[dt][r] *= cr[r];
      }

      float psum = 0.f;
      short4_ pk[4];
#pragma unroll
      for (int s = 0; s < 4; ++s) {
#pragma unroll
        for (int r = 0; r < 4; ++r) {
          const float p_ = __builtin_amdgcn_exp2f((sv[s][r] - mrun) * 1.44269504f);
          psum += p_;
          pk[s][r] = (short)f2bf(p_);
        }
      }
      psum += __shfl_xor(psum, 16);
      psum += __shfl_xor(psum, 32);
      lrun += psum;

      // ---- PV: A = P (in-lane), B = V^T via 2x b128 reads per dt ([g][s] layout) ----
      __builtin_amdgcn_s_setprio(1);
#pragma unroll
      for (int dt = 0; dt < 16; ++dt) {
        const int d = dt * 16 + lm;
        const int sw = ((d ^ (d >> 4)) & 14) << 3;
        const unsigned char* vr = &bV[d * 128];
        short8 v01 = *(const short8*)&vr[(g * 32) ^ sw];
        short8 v23 = *(const short8*)&vr[(g * 32 + 16) ^ sw];
        short4_ f0 = {v01[0], v01[1], v01[2], v01[3]};
        short4_ f1 = {v01[4], v01[5], v01[6], v01[7]};
        short4_ f2 = {v23[0], v23[1], v23[2], v23[3]};
        short4_ f3 = {v23[4], v23[5], v23[6], v23[7]};
        o[dt] = MFMA16(pk[0], f0, o[dt]);
        o[dt] = MFMA16(pk[1], f1, o[dt]);
        o[dt] = MFMA16(pk[2], f2, o[dt]);
        o[dt] = MFMA16(pk[3], f3, o[dt]);
      }
      __builtin_amdgcn_s_setprio(0);

      __syncthreads();  // staged STORE visible; all waves done reading bK/bV
      p ^= 1;
    }

    // ---- write unnormalized bf16 partial + stats for this chunk ----
    unsigned short* op =
        Pall + (size_t)h * BSD_TOT + (bS + (size_t)(qrow0 + w * 16)) * D_DIM;
#pragma unroll
    for (int dt = 0; dt < 16; ++dt)
#pragma unroll
      for (int r = 0; r < 4; ++r)
        op[(size_t)(g * 4 + r) * D_DIM + dt * 16 + lm] = f2bf(o[dt][r]);
    if (g == 0) {
      stats[(size_t)h * BS_TOT + bS + q_g] = mrun;
      stats[(size_t)(4 + h) * BS_TOT + bS + q_g] = lrun;
    }

    // ---- ticket: last split of this chunk combines the 4 partials ----
    __threadfence();  // release: partial + stats visible device-wide
    if (t == 0) {
      const int old = atomicAdd(&cnt[b * 32 + qc], 1);
      doComb = (old == 3);
    }
    __syncthreads();
    if (doComb) {
      __threadfence();  // acquire: other splits' partials visible
      const int rowl = t >> 2;          // 0..127
      const int d0 = (t & 3) * 64;      // 0,64,128,192
      const size_t gro = bS + (size_t)(qrow0 + rowl);
      const float m0 = stats[gro];
      const float m1 = stats[BS_TOT + gro];
      const float m2 = stats[2 * BS_TOT + gro];
      const float m3 = stats[3 * BS_TOT + gro];
      const float mm = fmaxf(fmaxf(m0, m1), fmaxf(m2, m3));
      const float s0 = __builtin_amdgcn_exp2f((m0 - mm) * 1.44269504f);
      const float s1 = __builtin_amdgcn_exp2f((m1 - mm) * 1.44269504f);
      const float s2 = __builtin_amdgcn_exp2f((m2 - mm) * 1.44269504f);
      const float s3 = __builtin_amdgcn_exp2f((m3 - mm) * 1.44269504f);
      const float denom = s0 * stats[4 * BS_TOT + gro] + s1 * stats[5 * BS_TOT + gro] +
                          s2 * stats[6 * BS_TOT + gro] + s3 * stats[7 * BS_TOT + gro];
      const float inv = 1.f / denom;
      const unsigned short* p0 = Pall + gro * D_DIM + d0;
      const unsigned short* p1 = p0 + BSD_TOT;
      const unsigned short* p2 = p0 + 2 * BSD_TOT;
      const unsigned short* p3 = p0 + 3 * BSD_TOT;
      float* oo = Out + gro * D_DIM + d0;
#pragma unroll
      for (int j = 0; j < 16; ++j) {
        ushort4_ a0 = *(const ushort4_*)(p0 + j * 4);
        ushort4_ a1 = *(const ushort4_*)(p1 + j * 4);
        ushort4_ a2 = *(const ushort4_*)(p2 + j * 4);
        ushort4_ a3 = *(const ushort4_*)(p3 + j * 4);
        f32x4 acc;
#pragma unroll
        for (int jj = 0; jj < 4; ++jj)
          acc[jj] = bf2f(a0[jj]) * s0 + bf2f(a1[jj]) * s1 + bf2f(a2[jj]) * s2 + bf2f(a3[jj]) * s3;
        *(f32x4*)oo = acc * inv;
        oo += 4;
      }
    }
    __syncthreads();  // doComb reuse + LDS reuse in next chunk
  }
#undef LOAD_TILE
#undef STORE_TILE
}

// ---------------- Fallback: single-pass attention (round-1, known good) ----------------
__global__ __launch_bounds__(256, 2)
void attn_kernel(const unsigned short* __restrict__ Qb,
                 const unsigned short* __restrict__ Kb,
                 const unsigned short* __restrict__ Vb,
                 const int* __restrict__ amask,
                 float* __restrict__ Out) {
  __shared__ __align__(16) unsigned char sK[32768];
  __shared__ __align__(16) unsigned char sVT[32768];

  const int t = (int)threadIdx.x;
  const int l = t & 63;
  const int w = t >> 6;
  const int lm = l & 15;
  const int g = l >> 4;
  const int b = (int)blockIdx.x >> 6;
  const int qb = (int)blockIdx.x & 63;
  const size_t bS = (size_t)b * S_LEN;

  short8 qf[8];
  {
    const unsigned short* qp = Qb + (bS + (size_t)(qb * 64 + w * 16 + lm)) * D_DIM + g * 8;
#pragma unroll
    for (int ch = 0; ch < 8; ++ch) qf[ch] = *(const short8*)(qp + ch * 32);
  }

  f32x4 o[16];
#pragma unroll
  for (int dt = 0; dt < 16; ++dt) o[dt] = (f32x4){0.f, 0.f, 0.f, 0.f};
  float mrun = -1e30f, lrun = 0.f;
  const int q_g = qb * 64 + w * 16 + lm;

  for (int tt = 0; tt <= qb; ++tt) {
    const int k0 = tt * 64;
#pragma unroll
    for (int i = 0; i < 8; ++i) {
      const int c = t + i * 256;
      const int row = c >> 5;
      const int d8 = (c & 31) << 3;
      {
        int4_ kvv = *(const int4_*)(Kb + (bS + (size_t)(k0 + row)) * D_DIM + d8);
        *(int4_*)&sK[row * 512 + ((d8 * 2) ^ ((row & 7) << 4))] = kvv;
      }
      {
        int4_ vvv = *(const int4_*)(Vb + (bS + (size_t)(k0 + row)) * D_DIM + d8);
        const unsigned short* pv = (const unsigned short*)&vvv;
#pragma unroll
        for (int jj = 0; jj < 8; ++jj) {
          const int d = d8 + jj;
          const int swz = (((d >> 4) ^ d) & 15) << 3;
          *(unsigned short*)&sVT[d * 128 + ((row * 2) ^ swz)] = pv[jj];
        }
      }
    }
    __syncthreads();

    f32x4 sacc[4];
#pragma unroll
    for (int s = 0; s < 4; ++s) sacc[s] = (f32x4){0.f, 0.f, 0.f, 0.f};
#pragma unroll
    for (int ch = 0; ch < 8; ++ch) {
#pragma unroll
      for (int s = 0; s < 4; ++s) {
        const int key = s * 16 + lm;
        const int off = key * 512 + (((ch * 32 + g * 8) * 2) ^ ((key & 7) << 4));
        short8 kf = *(const short8*)&sK[off];
        sacc[s] = __builtin_amdgcn_mfma_f32_16x16x32_bf16(kf, qf[ch], sacc[s], 0, 0, 0);
      }
    }

    float sv[4][4];
    float tmax = -1e30f;
#pragma unroll
    for (int s = 0; s < 4; ++s) {
      const int4_ mw = *(const int4_*)(amask + bS + k0 + s * 16 + g * 4);
#pragma unroll
      for (int r = 0; r < 4; ++r) {
        const int key_g = k0 + s * 16 + g * 4 + r;
        const bool ok = (key_g <= q_g) && (mw[r] != 0);
        const float x = ok ? sacc[s][r] : -1e30f;
        sv[s][r] = x;
        tmax = fmaxf(tmax, x);
      }
    }
    tmax = fmaxf(tmax, __shfl_xor(tmax, 16));
    tmax = fmaxf(tmax, __shfl_xor(tmax, 32));
    const float mnew = fmaxf(mrun, tmax);
    const float corr = __builtin_amdgcn_exp2f((mrun - mnew) * 1.44269504f);
    mrun = mnew;

    float psum = 0.f;
    short4_ pk[4];
#pragma unroll
    for (int s = 0; s < 4; ++s) {
#pragma unroll
      for (int r = 0; r < 4; ++r) {
        const float p = __builtin_amdgcn_exp2f((sv[s][r] - mnew) * 1.44269504f);
        psum += p;
        pk[s][r] = (short)f2bf(p);
      }
    }
    psum += __shfl_xor(psum, 16);
    psum += __shfl_xor(psum, 32);
    lrun = lrun * corr + psum;

    float cr[4];
#pragma unroll
    for (int r = 0; r < 4; ++r) cr[r] = __shfl(corr, g * 4 + r);
#pragma unroll
    for (int dt = 0; dt < 16; ++dt)
#pragma unroll
      for (int r = 0; r < 4; ++r) o[dt][r] *= cr[r];

#pragma unroll
    for (int dt = 0; dt < 16; ++dt) {
      const int d = dt * 16 + lm;
      const int swz = (((d >> 4) ^ d) & 15) << 3;
#pragma unroll
      for (int s = 0; s < 4; ++s) {
        short4_ vf = *(const short4_*)&sVT[d * 128 + ((s * 32 + g * 8) ^ swz)];
        o[dt] = MFMA16(pk[s], vf, o[dt]);
      }
    }
    __syncthreads();
  }

  const float inv = 1.f / lrun;
  float ir[4];
#pragma unroll
  for (int r = 0; r < 4; ++r) ir[r] = __shfl(inv, g * 4 + r);
  float* op = Out + (bS + (size_t)(qb * 64 + w * 16)) * D_DIM;
#pragma unroll
  for (int dt = 0; dt < 16; ++dt)
#pragma unroll
    for (int r = 0; r < 4; ++r)
      op[(size_t)(g * 4 + r) * D_DIM + dt * 16 + lm] = o[dt][r] * ir[r];
}

extern "C" void kernel_launch(void* const* d_in, const int* in_sizes, int n_in,
                              void* d_out, int out_size, void* d_ws, size_t ws_size,
                              hipStream_t stream) {
  const float* x_q = (const float*)d_in[0];
  const float* x_k = (const float*)d_in[1];
  const float* x_v = (const float*)d_in[2];
  const int* amask = (const int*)d_in[3];
  const float* Wq = (const float*)d_in[4];
  const float* Wk = (const float*)d_in[5];
  const float* Wv = (const float*)d_in[6];

  unsigned short* Qb = (unsigned short*)d_ws;
  unsigned short* Kb = Qb + BSD_TOT;
  unsigned short* Vb = Kb + BSD_TOT;

  dim3 pg(128, 2, 3);
  proj_kernel<<<pg, dim3(256), 0, stream>>>(x_q, x_k, x_v, Wq, Wk, Wv, Qb, Kb, Vb);

  const size_t qkv_bytes = 3 * BSD_TOT * sizeof(unsigned short);   // 25.2 MB
  const size_t pall_bytes = 4 * BSD_TOT * sizeof(unsigned short);  // 33.6 MB
  const size_t stat_bytes = 8 * (size_t)BS_TOT * sizeof(float);    // 512 KB
  const size_t flag_bytes = (size_t)B_N * 64 * sizeof(int);        // 1 KB
  const size_t cnt_bytes = (size_t)B_N * 32 * sizeof(int);         // 512 B
  if (ws_size >= qkv_bytes + pall_bytes + stat_bytes + flag_bytes + cnt_bytes) {
    unsigned short* Pall = (unsigned short*)((char*)d_ws + qkv_bytes);
    float* stats = (float*)((char*)d_ws + qkv_bytes + pall_bytes);
    int* tflags = (int*)((char*)d_ws + qkv_bytes + pall_bytes + stat_bytes);
    int* cnt = (int*)((char*)d_ws + qkv_bytes + pall_bytes + stat_bytes + flag_bytes);
    hipMemsetAsync(cnt, 0, cnt_bytes, stream);
    mask_flags_kernel<<<dim3(B_N), dim3(64), 0, stream>>>(amask, tflags);
    attn_split4_kernel<<<dim3(256), dim3(512), 0, stream>>>(
        Qb, Kb, Vb, amask, tflags, Pall, stats, cnt, (float*)d_out);
  } else {
    attn_kernel<<<dim3(B_N * (S_LEN / 64)), dim3(256), 0, stream>>>(Qb, Kb, Vb, amask,
                                                                    (float*)d_out);
  }
}

// Round 16
// 98.782 us; speedup vs baseline: 2.8545x; 2.8545x over previous
//
#include <hip/hip_runtime.h>

#define B_N 4
#define S_LEN 4096
#define D_DIM 256
#define BS_TOT (B_N * S_LEN)
#define BSD_TOT ((size_t)BS_TOT * D_DIM)

typedef __attribute__((ext_vector_type(8))) short short8;
typedef __attribute__((ext_vector_type(4))) short short4_;
typedef __attribute__((ext_vector_type(4))) unsigned short ushort4_;
typedef __attribute__((ext_vector_type(4))) float f32x4;
typedef __attribute__((ext_vector_type(4))) int int4_;

static __device__ __forceinline__ unsigned short f2bf(float f) {
  unsigned u = __builtin_bit_cast(unsigned, f);
  u += 0x7fffu + ((u >> 16) & 1u);
  return (unsigned short)(u >> 16);
}
static __device__ __forceinline__ float bf2f(unsigned short h) {
  unsigned u = ((unsigned)h) << 16;
  return __builtin_bit_cast(float, u);
}

#if __has_builtin(__builtin_amdgcn_mfma_f32_16x16x16bf16_1k)
#define MFMA16(a, b, c) __builtin_amdgcn_mfma_f32_16x16x16bf16_1k((a), (b), (c), 0, 0, 0)
#else
static __device__ __forceinline__ f32x4 mfma16_asm(short4_ a, short4_ b, f32x4 c) {
  asm volatile("v_mfma_f32_16x16x16_bf16 %0, %1, %2, %0" : "+v"(c) : "v"(a), "v"(b));
  return c;
}
#define MFMA16(a, b, c) mfma16_asm((a), (b), (c))
#endif

// ---------------- Projection: Out[m][n] = sum_k X[m][k] * W[n][k]  (bf16 out) ----------------
// r12 tiling (128x128, grid 128x2x3). Side job: 4 blocks also compute per-tile mask flags.
__global__ __launch_bounds__(256, 2)
void proj_kernel(const float* __restrict__ X0, const float* __restrict__ X1,
                 const float* __restrict__ X2,
                 const float* __restrict__ W0, const float* __restrict__ W1,
                 const float* __restrict__ W2,
                 unsigned short* __restrict__ O0, unsigned short* __restrict__ O1,
                 unsigned short* __restrict__ O2,
                 const int* __restrict__ amask, int* __restrict__ flags) {
  __shared__ __align__(16) unsigned char sA[16384];
  __shared__ __align__(16) unsigned char sB[16384];

  const int z = (int)blockIdx.z;
  const float* X = (z == 0) ? X0 : (z == 1) ? X1 : X2;
  const float* W = (z == 0) ? W0 : (z == 1) ? W1 : W2;
  unsigned short* O = (z == 0) ? O0 : (z == 1) ? O1 : O2;
  const float mult = (z == 0) ? 0.0625f : 1.0f;  // fold 1/sqrt(D) into Q

  const int t = (int)threadIdx.x;
  const int l = t & 63, w = t >> 6;
  const int lm = l & 15, g = l >> 4;
  const int wr = w >> 1, wc = w & 1;
  const int mb = (int)blockIdx.x * 128;
  const int nb = (int)blockIdx.y * 128;

  // side job: mask flags (4 blocks of the grid)
  if (z == 0 && (int)blockIdx.y == 0 && (int)blockIdx.x < B_N && t < 64) {
    const int4_* p = (const int4_*)(amask + ((size_t)blockIdx.x * 64 + t) * 64);
    int all1 = 1;
#pragma unroll
    for (int i = 0; i < 16; ++i) {
      int4_ v = p[i];
      all1 &= (v[0] != 0) & (v[1] != 0) & (v[2] != 0) & (v[3] != 0);
    }
    flags[(int)blockIdx.x * 64 + t] = all1;
  }

  f32x4 acc[4][4];
#pragma unroll
  for (int i = 0; i < 4; ++i)
#pragma unroll
    for (int j = 0; j < 4; ++j) acc[i][j] = (f32x4){0.f, 0.f, 0.f, 0.f};

  for (int ks = 0; ks < 4; ++ks) {
    const int k0 = ks * 64;
#pragma unroll
    for (int i = 0; i < 4; ++i) {
      const int c = t + i * 256;
      const int row = c >> 3;
      const int kc = (c & 7) * 8;
      const float* xp = X + (size_t)(mb + row) * D_DIM + k0 + kc;
      const float* wp = W + (size_t)(nb + row) * D_DIM + k0 + kc;
      f32x4 x0 = *(const f32x4*)xp;
      f32x4 x1 = *(const f32x4*)(xp + 4);
      f32x4 w0 = *(const f32x4*)wp;
      f32x4 w1 = *(const f32x4*)(wp + 4);
      short8 xa, wa;
#pragma unroll
      for (int j = 0; j < 4; ++j) {
        xa[j] = (short)f2bf(x0[j]);
        xa[j + 4] = (short)f2bf(x1[j]);
        wa[j] = (short)f2bf(w0[j]);
        wa[j + 4] = (short)f2bf(w1[j]);
      }
      const int off = row * 128 + ((kc * 2) ^ ((row & 7) << 4));
      *(short8*)&sA[off] = xa;
      *(short8*)&sB[off] = wa;
    }
    __syncthreads();
#pragma unroll
    for (int kk = 0; kk < 2; ++kk) {
      short8 af[4], bg[4];
#pragma unroll
      for (int mi = 0; mi < 4; ++mi) {
        const int row = wr * 64 + mi * 16 + lm;
        af[mi] = *(const short8*)&sA[row * 128 + (((kk * 32 + g * 8) * 2) ^ ((row & 7) << 4))];
      }
#pragma unroll
      for (int ni = 0; ni < 4; ++ni) {
        const int row = wc * 64 + ni * 16 + lm;
        bg[ni] = *(const short8*)&sB[row * 128 + (((kk * 32 + g * 8) * 2) ^ ((row & 7) << 4))];
      }
#pragma unroll
      for (int mi = 0; mi < 4; ++mi)
#pragma unroll
        for (int ni = 0; ni < 4; ++ni)
          acc[mi][ni] = __builtin_amdgcn_mfma_f32_16x16x32_bf16(af[mi], bg[ni], acc[mi][ni], 0, 0, 0);
    }
    __syncthreads();
  }

#pragma unroll
  for (int mi = 0; mi < 4; ++mi)
#pragma unroll
    for (int ni = 0; ni < 4; ++ni)
#pragma unroll
      for (int r = 0; r < 4; ++r) {
        const int mg = mb + wr * 64 + mi * 16 + g * 4 + r;
        const int ng = nb + wc * 64 + ni * 16 + lm;
        O[(size_t)mg * D_DIM + ng] = f2bf(acc[mi][ni][r] * mult);
      }
}

// ---------------- Flash attention: QBLK=128, chunk-pair per block, split-4, XCD-local blocks ----------------
// V^T LDS row layout: within each 128B d-row, key k = s*16+g*4+r lives at byte g*32 + s*8 + r*2,
// XOR-swizzled at 16B granule by ((d^(d>>4))&14)<<3. PV reads 2x b128 per (dt): s={0,1} and s={2,3}.
__global__ __launch_bounds__(512, 2)
void attn_split4_kernel(const unsigned short* __restrict__ Qb,
                        const unsigned short* __restrict__ Kb,
                        const unsigned short* __restrict__ Vb,
                        const int* __restrict__ amask,
                        const int* __restrict__ tflags,
                        unsigned short* __restrict__ Pall,  // 4 bf16 partials [h][B*S][D]
                        float* __restrict__ stats)          // m[4][B*S], l[4][B*S]
{
  // per buffer: K at [0,32768), V^T at [32768,65536)
  __shared__ __align__(16) unsigned char sBuf[2][65536];

  const int t = (int)threadIdx.x;
  const int l = t & 63;
  const int w = t >> 6;  // 0..7
  const int lm = l & 15;
  const int g = l >> 4;

  const int lin = (int)blockIdx.x;          // 0..255
  const int xcd = lin & 7;
  const int jslot = lin >> 3;               // 0..31
  const int b = xcd >> 1;                   // batch pinned to an XCD pair
  const int slot = (xcd & 1) * 32 + jslot;  // 0..63
  const int pp = slot >> 2;                 // pair index 0..15
  const int h = slot & 3;                   // split 0..3
  const size_t bS = (size_t)b * S_LEN;

  int4_ kreg[4], vreg[4];
  const int crow = t >> 5;        // 0..15: this thread owns key-rows crow*4 .. crow*4+3
  const int cd8 = (t & 31) << 3;  // d chunk start
  const int vko = (crow & 3) * 32 + (crow >> 2) * 8;  // [g][s] byte offset of this thread's 4 keys

#define LOAD_TILE(T0)                                                              \
  do {                                                                             \
    const size_t kb_ = bS + (size_t)((T0)*64);                                     \
    _Pragma("unroll") for (int i_ = 0; i_ < 4; ++i_) {                             \
      kreg[i_] = *(const int4_*)(Kb + (kb_ + crow * 4 + i_) * D_DIM + cd8);        \
      vreg[i_] = *(const int4_*)(Vb + (kb_ + crow * 4 + i_) * D_DIM + cd8);        \
    }                                                                              \
  } while (0)

#define STORE_TILE(BUF)                                                            \
  do {                                                                             \
    unsigned char* bK_ = (BUF);                                                    \
    unsigned char* bV_ = (BUF) + 32768;                                            \
    _Pragma("unroll") for (int i_ = 0; i_ < 4; ++i_) {                             \
      const int row_ = crow * 4 + i_;                                              \
      *(int4_*)&bK_[row_ * 512 + ((cd8 * 2) ^ ((row_ & 7) << 4))] = kreg[i_];      \
    }                                                                              \
    const unsigned short* v0_ = (const unsigned short*)&vreg[0];                   \
    const unsigned short* v1_ = (const unsigned short*)&vreg[1];                   \
    const unsigned short* v2_ = (const unsigned short*)&vreg[2];                   \
    const unsigned short* v3_ = (const unsigned short*)&vreg[3];                   \
    _Pragma("unroll") for (int jj_ = 0; jj_ < 8; ++jj_) {                          \
      const int d_ = cd8 + jj_;                                                    \
      const int sw_ = ((d_ ^ (d_ >> 4)) & 14) << 3;                                \
      short4_ pv_;                                                                 \
      pv_[0] = (short)v0_[jj_]; pv_[1] = (short)v1_[jj_];                          \
      pv_[2] = (short)v2_[jj_]; pv_[3] = (short)v3_[jj_];                          \
      *(short4_*)&bV_[d_ * 128 + (vko ^ sw_)] = pv_;                               \
    }                                                                              \
  } while (0)

  for (int ci = 0; ci < 2; ++ci) {
    const int qc = ci ? (31 - pp) : pp;
    const int last = 2 * qc + 1;
    const int qrow0 = qc * 128;
    const int q_g = qrow0 + w * 16 + lm;

    // Q fragments (B-operand of swapped QK^T): q = lm, k-chunk = ch*32 + g*8 + j
    short8 qf[8];
    {
      const unsigned short* qp = Qb + (bS + (size_t)(qrow0 + w * 16 + lm)) * D_DIM + g * 8;
#pragma unroll
      for (int ch = 0; ch < 8; ++ch) qf[ch] = *(const short8*)(qp + ch * 32);
    }

    f32x4 o[16];
#pragma unroll
    for (int dt = 0; dt < 16; ++dt) o[dt] = (f32x4){0.f, 0.f, 0.f, 0.f};
    float mrun = -1e30f, lrun = 0.f;

    // prologue: stage tile h into buf0; prefetch tile h+4 into regs
    if (h <= last) {
      LOAD_TILE(h);
      STORE_TILE(sBuf[0]);
      if (h + 4 <= last) LOAD_TILE(h + 4);
    }
    __syncthreads();

    int p = 0;
    for (int tt = h; tt <= last; tt += 4) {
      const int k0 = tt * 64;
      const unsigned char* bK = sBuf[p];
      const unsigned char* bV = sBuf[p] + 32768;

      // stage NEXT tile from regs, then issue loads for the one after (land during compute)
      if (tt + 4 <= last) {
        STORE_TILE(sBuf[p ^ 1]);
        if (tt + 8 <= last) LOAD_TILE(tt + 8);
      }

      // ---- QK^T (S^T = K * Q^T): C col = q (lm), C row = key-in-16 (g*4+r) ----
      f32x4 sacc[4];
#pragma unroll
      for (int s = 0; s < 4; ++s) sacc[s] = (f32x4){0.f, 0.f, 0.f, 0.f};
      __builtin_amdgcn_s_setprio(1);
#pragma unroll
      for (int ch = 0; ch < 8; ++ch) {
#pragma unroll
        for (int s = 0; s < 4; ++s) {
          const int key = s * 16 + lm;
          const int off = key * 512 + (((ch * 32 + g * 8) * 2) ^ ((key & 7) << 4));
          short8 kf = *(const short8*)&bK[off];
          sacc[s] = __builtin_amdgcn_mfma_f32_16x16x32_bf16(kf, qf[ch], sacc[s], 0, 0, 0);
        }
      }
      __builtin_amdgcn_s_setprio(0);

      // ---- online softmax (stats per q = lm, replicated across 4 lane groups) ----
      float sv[4][4];
      float tmax = -1e30f;
      const bool fastm = tflags[b * 64 + tt] && (k0 + 63 <= qrow0 + w * 16);
      if (fastm) {
#pragma unroll
        for (int s = 0; s < 4; ++s)
#pragma unroll
          for (int r = 0; r < 4; ++r) {
            sv[s][r] = sacc[s][r];
            tmax = fmaxf(tmax, sacc[s][r]);
          }
      } else {
#pragma unroll
        for (int s = 0; s < 4; ++s) {
          const int4_ mw = *(const int4_*)(amask + bS + k0 + s * 16 + g * 4);
#pragma unroll
          for (int r = 0; r < 4; ++r) {
            const int key_g = k0 + s * 16 + g * 4 + r;
            const bool ok = (key_g <= q_g) && (mw[r] != 0);
            const float x = ok ? sacc[s][r] : -1e30f;
            sv[s][r] = x;
            tmax = fmaxf(tmax, x);
          }
        }
      }
      tmax = fmaxf(tmax, __shfl_xor(tmax, 16));
      tmax = fmaxf(tmax, __shfl_xor(tmax, 32));

      // defer-rescale: exact skip when no row's max grew (corr == 1 for all lanes)
      if (__ballot(tmax > mrun)) {
        const float mnew = fmaxf(mrun, tmax);
        const float corr = __builtin_amdgcn_exp2f((mrun - mnew) * 1.44269504f);
        mrun = mnew;
        lrun *= corr;
        float cr[4];
#pragma unroll
        for (int r = 0; r < 4; ++r) cr[r] = __shfl(corr, g * 4 + r);
#pragma unroll
        for (int dt = 0; dt < 16; ++dt)
#pragma unroll
          for (int r = 0; r < 4; ++r) o[dt][r] *= cr[r];
      }

      float psum = 0.f;
      short4_ pk[4];
#pragma unroll
      for (int s = 0; s < 4; ++s) {
#pragma unroll
        for (int r = 0; r < 4; ++r) {
          const float p_ = __builtin_amdgcn_exp2f((sv[s][r] - mrun) * 1.44269504f);
          psum += p_;
          pk[s][r] = (short)f2bf(p_);
        }
      }
      psum += __shfl_xor(psum, 16);
      psum += __shfl_xor(psum, 32);
      lrun += psum;

      // ---- PV: A = P (in-lane), B = V^T via 2x b128 reads per dt ([g][s] layout) ----
      __builtin_amdgcn_s_setprio(1);
#pragma unroll
      for (int dt = 0; dt < 16; ++dt) {
        const int d = dt * 16 + lm;
        const int sw = ((d ^ (d >> 4)) & 14) << 3;
        const unsigned char* vr = &bV[d * 128];
        short8 v01 = *(const short8*)&vr[(g * 32) ^ sw];
        short8 v23 = *(const short8*)&vr[(g * 32 + 16) ^ sw];
        short4_ f0 = {v01[0], v01[1], v01[2], v01[3]};
        short4_ f1 = {v01[4], v01[5], v01[6], v01[7]};
        short4_ f2 = {v23[0], v23[1], v23[2], v23[3]};
        short4_ f3 = {v23[4], v23[5], v23[6], v23[7]};
        o[dt] = MFMA16(pk[0], f0, o[dt]);
        o[dt] = MFMA16(pk[1], f1, o[dt]);
        o[dt] = MFMA16(pk[2], f2, o[dt]);
        o[dt] = MFMA16(pk[3], f3, o[dt]);
      }
      __builtin_amdgcn_s_setprio(0);

      __syncthreads();  // staged STORE visible; all waves done reading bK/bV
      p ^= 1;
    }

    // ---- write unnormalized bf16 partial + stats for this chunk ----
    unsigned short* op =
        Pall + (size_t)h * BSD_TOT + (bS + (size_t)(qrow0 + w * 16)) * D_DIM;
#pragma unroll
    for (int dt = 0; dt < 16; ++dt)
#pragma unroll
      for (int r = 0; r < 4; ++r)
        op[(size_t)(g * 4 + r) * D_DIM + dt * 16 + lm] = f2bf(o[dt][r]);
    if (g == 0) {
      stats[(size_t)h * BS_TOT + bS + q_g] = mrun;
      stats[(size_t)(4 + h) * BS_TOT + bS + q_g] = lrun;
    }
  }
#undef LOAD_TILE
#undef STORE_TILE
}

// ---------------- Combine 4 bf16 partials -> f32 output ----------------
__global__ __launch_bounds__(256)
void combine4_kernel(float* __restrict__ Out, const unsigned short* __restrict__ Pall,
                     const float* __restrict__ stats) {
  const int idx = (int)blockIdx.x * 256 + (int)threadIdx.x;  // one f32x4 / 4 bf16
  const int row = idx >> 6;
  const float m0 = stats[row];
  const float m1 = stats[BS_TOT + row];
  const float m2 = stats[2 * BS_TOT + row];
  const float m3 = stats[3 * BS_TOT + row];
  const float mm = fmaxf(fmaxf(m0, m1), fmaxf(m2, m3));
  const float s0 = __builtin_amdgcn_exp2f((m0 - mm) * 1.44269504f);
  const float s1 = __builtin_amdgcn_exp2f((m1 - mm) * 1.44269504f);
  const float s2 = __builtin_amdgcn_exp2f((m2 - mm) * 1.44269504f);
  const float s3 = __builtin_amdgcn_exp2f((m3 - mm) * 1.44269504f);
  const float denom = s0 * stats[4 * BS_TOT + row] + s1 * stats[5 * BS_TOT + row] +
                      s2 * stats[6 * BS_TOT + row] + s3 * stats[7 * BS_TOT + row];
  const float inv = 1.f / denom;

  ushort4_ u0 = *(const ushort4_*)(Pall + (size_t)idx * 4);
  ushort4_ u1 = *(const ushort4_*)(Pall + BSD_TOT + (size_t)idx * 4);
  ushort4_ u2 = *(const ushort4_*)(Pall + 2 * BSD_TOT + (size_t)idx * 4);
  ushort4_ u3 = *(const ushort4_*)(Pall + 3 * BSD_TOT + (size_t)idx * 4);
  f32x4 acc;
#pragma unroll
  for (int j = 0; j < 4; ++j)
    acc[j] = bf2f(u0[j]) * s0 + bf2f(u1[j]) * s1 + bf2f(u2[j]) * s2 + bf2f(u3[j]) * s3;
  *(f32x4*)(Out + (size_t)idx * 4) = acc * inv;
}

// ---------------- Fallback: single-pass attention (round-1, known good) ----------------
__global__ __launch_bounds__(256, 2)
void attn_kernel(const unsigned short* __restrict__ Qb,
                 const unsigned short* __restrict__ Kb,
                 const unsigned short* __restrict__ Vb,
                 const int* __restrict__ amask,
                 float* __restrict__ Out) {
  __shared__ __align__(16) unsigned char sK[32768];
  __shared__ __align__(16) unsigned char sVT[32768];

  const int t = (int)threadIdx.x;
  const int l = t & 63;
  const int w = t >> 6;
  const int lm = l & 15;
  const int g = l >> 4;
  const int b = (int)blockIdx.x >> 6;
  const int qb = (int)blockIdx.x & 63;
  const size_t bS = (size_t)b * S_LEN;

  short8 qf[8];
  {
    const unsigned short* qp = Qb + (bS + (size_t)(qb * 64 + w * 16 + lm)) * D_DIM + g * 8;
#pragma unroll
    for (int ch = 0; ch < 8; ++ch) qf[ch] = *(const short8*)(qp + ch * 32);
  }

  f32x4 o[16];
#pragma unroll
  for (int dt = 0; dt < 16; ++dt) o[dt] = (f32x4){0.f, 0.f, 0.f, 0.f};
  float mrun = -1e30f, lrun = 0.f;
  const int q_g = qb * 64 + w * 16 + lm;

  for (int tt = 0; tt <= qb; ++tt) {
    const int k0 = tt * 64;
#pragma unroll
    for (int i = 0; i < 8; ++i) {
      const int c = t + i * 256;
      const int row = c >> 5;
      const int d8 = (c & 31) << 3;
      {
        int4_ kvv = *(const int4_*)(Kb + (bS + (size_t)(k0 + row)) * D_DIM + d8);
        *(int4_*)&sK[row * 512 + ((d8 * 2) ^ ((row & 7) << 4))] = kvv;
      }
      {
        int4_ vvv = *(const int4_*)(Vb + (bS + (size_t)(k0 + row)) * D_DIM + d8);
        const unsigned short* pv = (const unsigned short*)&vvv;
#pragma unroll
        for (int jj = 0; jj < 8; ++jj) {
          const int d = d8 + jj;
          const int swz = (((d >> 4) ^ d) & 15) << 3;
          *(unsigned short*)&sVT[d * 128 + ((row * 2) ^ swz)] = pv[jj];
        }
      }
    }
    __syncthreads();

    f32x4 sacc[4];
#pragma unroll
    for (int s = 0; s < 4; ++s) sacc[s] = (f32x4){0.f, 0.f, 0.f, 0.f};
#pragma unroll
    for (int ch = 0; ch < 8; ++ch) {
#pragma unroll
      for (int s = 0; s < 4; ++s) {
        const int key = s * 16 + lm;
        const int off = key * 512 + (((ch * 32 + g * 8) * 2) ^ ((key & 7) << 4));
        short8 kf = *(const short8*)&sK[off];
        sacc[s] = __builtin_amdgcn_mfma_f32_16x16x32_bf16(kf, qf[ch], sacc[s], 0, 0, 0);
      }
    }

    float sv[4][4];
    float tmax = -1e30f;
#pragma unroll
    for (int s = 0; s < 4; ++s) {
      const int4_ mw = *(const int4_*)(amask + bS + k0 + s * 16 + g * 4);
#pragma unroll
      for (int r = 0; r < 4; ++r) {
        const int key_g = k0 + s * 16 + g * 4 + r;
        const bool ok = (key_g <= q_g) && (mw[r] != 0);
        const float x = ok ? sacc[s][r] : -1e30f;
        sv[s][r] = x;
        tmax = fmaxf(tmax, x);
      }
    }
    tmax = fmaxf(tmax, __shfl_xor(tmax, 16));
    tmax = fmaxf(tmax, __shfl_xor(tmax, 32));
    const float mnew = fmaxf(mrun, tmax);
    const float corr = __builtin_amdgcn_exp2f((mrun - mnew) * 1.44269504f);
    mrun = mnew;

    float psum = 0.f;
    short4_ pk[4];
#pragma unroll
    for (int s = 0; s < 4; ++s) {
#pragma unroll
      for (int r = 0; r < 4; ++r) {
        const float p = __builtin_amdgcn_exp2f((sv[s][r] - mnew) * 1.44269504f);
        psum += p;
        pk[s][r] = (short)f2bf(p);
      }
    }
    psum += __shfl_xor(psum, 16);
    psum += __shfl_xor(psum, 32);
    lrun = lrun * corr + psum;

    float cr[4];
#pragma unroll
    for (int r = 0; r < 4; ++r) cr[r] = __shfl(corr, g * 4 + r);
#pragma unroll
    for (int dt = 0; dt < 16; ++dt)
#pragma unroll
      for (int r = 0; r < 4; ++r) o[dt][r] *= cr[r];

#pragma unroll
    for (int dt = 0; dt < 16; ++dt) {
      const int d = dt * 16 + lm;
      const int swz = (((d >> 4) ^ d) & 15) << 3;
#pragma unroll
      for (int s = 0; s < 4; ++s) {
        short4_ vf = *(const short4_*)&sVT[d * 128 + ((s * 32 + g * 8) ^ swz)];
        o[dt] = MFMA16(pk[s], vf, o[dt]);
      }
    }
    __syncthreads();
  }

  const float inv = 1.f / lrun;
  float ir[4];
#pragma unroll
  for (int r = 0; r < 4; ++r) ir[r] = __shfl(inv, g * 4 + r);
  float* op = Out + (bS + (size_t)(qb * 64 + w * 16)) * D_DIM;
#pragma unroll
  for (int dt = 0; dt < 16; ++dt)
#pragma unroll
    for (int r = 0; r < 4; ++r)
      op[(size_t)(g * 4 + r) * D_DIM + dt * 16 + lm] = o[dt][r] * ir[r];
}

extern "C" void kernel_launch(void* const* d_in, const int* in_sizes, int n_in,
                              void* d_out, int out_size, void* d_ws, size_t ws_size,
                              hipStream_t stream) {
  const float* x_q = (const float*)d_in[0];
  const float* x_k = (const float*)d_in[1];
  const float* x_v = (const float*)d_in[2];
  const int* amask = (const int*)d_in[3];
  const float* Wq = (const float*)d_in[4];
  const float* Wk = (const float*)d_in[5];
  const float* Wv = (const float*)d_in[6];

  unsigned short* Qb = (unsigned short*)d_ws;
  unsigned short* Kb = Qb + BSD_TOT;
  unsigned short* Vb = Kb + BSD_TOT;

  const size_t qkv_bytes = 3 * BSD_TOT * sizeof(unsigned short);   // 25.2 MB
  const size_t pall_bytes = 4 * BSD_TOT * sizeof(unsigned short);  // 33.6 MB
  const size_t stat_bytes = 8 * (size_t)BS_TOT * sizeof(float);    // 512 KB
  const size_t flag_bytes = (size_t)B_N * 64 * sizeof(int);        // 1 KB
  if (ws_size >= qkv_bytes + pall_bytes + stat_bytes + flag_bytes) {
    unsigned short* Pall = (unsigned short*)((char*)d_ws + qkv_bytes);
    float* stats = (float*)((char*)d_ws + qkv_bytes + pall_bytes);
    int* tflags = (int*)((char*)d_ws + qkv_bytes + pall_bytes + stat_bytes);
    dim3 pg(128, 2, 3);
    proj_kernel<<<pg, dim3(256), 0, stream>>>(x_q, x_k, x_v, Wq, Wk, Wv, Qb, Kb, Vb,
                                              amask, tflags);
    attn_split4_kernel<<<dim3(256), dim3(512), 0, stream>>>(
        Qb, Kb, Vb, amask, tflags, Pall, stats);
    combine4_kernel<<<dim3((unsigned)(BSD_TOT / 4 / 256)), dim3(256), 0, stream>>>(
        (float*)d_out, Pall, stats);
  } else {
    dim3 pg(128, 2, 3);
    proj_kernel<<<pg, dim3(256), 0, stream>>>(x_q, x_k, x_v, Wq, Wk, Wv, Qb, Kb, Vb,
                                              amask, (int*)((char*)d_ws + qkv_bytes));
    attn_kernel<<<dim3(B_N * (S_LEN / 64)), dim3(256), 0, stream>>>(Qb, Kb, Vb, amask,
                                                                    (float*)d_out);
  }
}

// Round 17
// 95.627 us; speedup vs baseline: 2.9487x; 1.0330x over previous
//
#include <hip/hip_runtime.h>

#define B_N 4
#define S_LEN 4096
#define D_DIM 256
#define BS_TOT (B_N * S_LEN)
#define BSD_TOT ((size_t)BS_TOT * D_DIM)

typedef __attribute__((ext_vector_type(8))) short short8;
typedef __attribute__((ext_vector_type(4))) short short4_;
typedef __attribute__((ext_vector_type(4))) unsigned short ushort4_;
typedef __attribute__((ext_vector_type(4))) float f32x4;
typedef __attribute__((ext_vector_type(4))) int int4_;

static __device__ __forceinline__ unsigned short f2bf(float f) {
  unsigned u = __builtin_bit_cast(unsigned, f);
  u += 0x7fffu + ((u >> 16) & 1u);
  return (unsigned short)(u >> 16);
}
static __device__ __forceinline__ float bf2f(unsigned short h) {
  unsigned u = ((unsigned)h) << 16;
  return __builtin_bit_cast(float, u);
}

#if __has_builtin(__builtin_amdgcn_mfma_f32_16x16x16bf16_1k)
#define MFMA16(a, b, c) __builtin_amdgcn_mfma_f32_16x16x16bf16_1k((a), (b), (c), 0, 0, 0)
#else
static __device__ __forceinline__ f32x4 mfma16_asm(short4_ a, short4_ b, f32x4 c) {
  asm volatile("v_mfma_f32_16x16x16_bf16 %0, %1, %2, %0" : "+v"(c) : "v"(a), "v"(b));
  return c;
}
#define MFMA16(a, b, c) mfma16_asm((a), (b), (c))
#endif

// ---------------- Projection: Out[m][n] = sum_k X[m][k] * W[n][k]  (bf16 out) ----------------
// r12 tiling (128x128, grid 128x2x3). Side job: 4 blocks also compute per-tile mask flags.
__global__ __launch_bounds__(256, 2)
void proj_kernel(const float* __restrict__ X0, const float* __restrict__ X1,
                 const float* __restrict__ X2,
                 const float* __restrict__ W0, const float* __restrict__ W1,
                 const float* __restrict__ W2,
                 unsigned short* __restrict__ O0, unsigned short* __restrict__ O1,
                 unsigned short* __restrict__ O2,
                 const int* __restrict__ amask, int* __restrict__ flags) {
  __shared__ __align__(16) unsigned char sA[16384];
  __shared__ __align__(16) unsigned char sB[16384];

  const int z = (int)blockIdx.z;
  const float* X = (z == 0) ? X0 : (z == 1) ? X1 : X2;
  const float* W = (z == 0) ? W0 : (z == 1) ? W1 : W2;
  unsigned short* O = (z == 0) ? O0 : (z == 1) ? O1 : O2;
  const float mult = (z == 0) ? 0.0625f : 1.0f;  // fold 1/sqrt(D) into Q

  const int t = (int)threadIdx.x;
  const int l = t & 63, w = t >> 6;
  const int lm = l & 15, g = l >> 4;
  const int wr = w >> 1, wc = w & 1;
  const int mb = (int)blockIdx.x * 128;
  const int nb = (int)blockIdx.y * 128;

  // side job: mask flags (4 blocks of the grid)
  if (z == 0 && (int)blockIdx.y == 0 && (int)blockIdx.x < B_N && t < 64) {
    const int4_* p = (const int4_*)(amask + ((size_t)blockIdx.x * 64 + t) * 64);
    int all1 = 1;
#pragma unroll
    for (int i = 0; i < 16; ++i) {
      int4_ v = p[i];
      all1 &= (v[0] != 0) & (v[1] != 0) & (v[2] != 0) & (v[3] != 0);
    }
    flags[(int)blockIdx.x * 64 + t] = all1;
  }

  f32x4 acc[4][4];
#pragma unroll
  for (int i = 0; i < 4; ++i)
#pragma unroll
    for (int j = 0; j < 4; ++j) acc[i][j] = (f32x4){0.f, 0.f, 0.f, 0.f};

  for (int ks = 0; ks < 4; ++ks) {
    const int k0 = ks * 64;
#pragma unroll
    for (int i = 0; i < 4; ++i) {
      const int c = t + i * 256;
      const int row = c >> 3;
      const int kc = (c & 7) * 8;
      const float* xp = X + (size_t)(mb + row) * D_DIM + k0 + kc;
      const float* wp = W + (size_t)(nb + row) * D_DIM + k0 + kc;
      f32x4 x0 = *(const f32x4*)xp;
      f32x4 x1 = *(const f32x4*)(xp + 4);
      f32x4 w0 = *(const f32x4*)wp;
      f32x4 w1 = *(const f32x4*)(wp + 4);
      short8 xa, wa;
#pragma unroll
      for (int j = 0; j < 4; ++j) {
        xa[j] = (short)f2bf(x0[j]);
        xa[j + 4] = (short)f2bf(x1[j]);
        wa[j] = (short)f2bf(w0[j]);
        wa[j + 4] = (short)f2bf(w1[j]);
      }
      const int off = row * 128 + ((kc * 2) ^ ((row & 7) << 4));
      *(short8*)&sA[off] = xa;
      *(short8*)&sB[off] = wa;
    }
    __syncthreads();
#pragma unroll
    for (int kk = 0; kk < 2; ++kk) {
      short8 af[4], bg[4];
#pragma unroll
      for (int mi = 0; mi < 4; ++mi) {
        const int row = wr * 64 + mi * 16 + lm;
        af[mi] = *(const short8*)&sA[row * 128 + (((kk * 32 + g * 8) * 2) ^ ((row & 7) << 4))];
      }
#pragma unroll
      for (int ni = 0; ni < 4; ++ni) {
        const int row = wc * 64 + ni * 16 + lm;
        bg[ni] = *(const short8*)&sB[row * 128 + (((kk * 32 + g * 8) * 2) ^ ((row & 7) << 4))];
      }
#pragma unroll
      for (int mi = 0; mi < 4; ++mi)
#pragma unroll
        for (int ni = 0; ni < 4; ++ni)
          acc[mi][ni] = __builtin_amdgcn_mfma_f32_16x16x32_bf16(af[mi], bg[ni], acc[mi][ni], 0, 0, 0);
    }
    __syncthreads();
  }

#pragma unroll
  for (int mi = 0; mi < 4; ++mi)
#pragma unroll
    for (int ni = 0; ni < 4; ++ni)
#pragma unroll
      for (int r = 0; r < 4; ++r) {
        const int mg = mb + wr * 64 + mi * 16 + g * 4 + r;
        const int ng = nb + wc * 64 + ni * 16 + lm;
        O[(size_t)mg * D_DIM + ng] = f2bf(acc[mi][ni][r] * mult);
      }
}

// ---------------- Flash attention: QBLK=128, chunk-pair per block, split-4, XCD-local blocks ----------------
// V^T LDS row layout: within each 128B d-row, key k = s*16+g*4+r lives at byte g*32 + s*8 + r*2,
// XOR-swizzled at 16B granule by ((d^(d>>4))&14)<<3. PV reads 2x b128 per (dt): s={0,1} and s={2,3}.
// Defer-rescale THR=8 (T13): skip O-rescale while max growth <= 8; P bounded by e^8, bf16 error
// stays relative so combine math is scale-invariant.
__global__ __launch_bounds__(512, 2)
void attn_split4_kernel(const unsigned short* __restrict__ Qb,
                        const unsigned short* __restrict__ Kb,
                        const unsigned short* __restrict__ Vb,
                        const int* __restrict__ amask,
                        const int* __restrict__ tflags,
                        unsigned short* __restrict__ Pall,  // 4 bf16 partials [h][B*S][D]
                        float* __restrict__ stats)          // m[4][B*S], l[4][B*S]
{
  // per buffer: K at [0,32768), V^T at [32768,65536)
  __shared__ __align__(16) unsigned char sBuf[2][65536];

  const int t = (int)threadIdx.x;
  const int l = t & 63;
  const int w = t >> 6;  // 0..7
  const int lm = l & 15;
  const int g = l >> 4;

  const int lin = (int)blockIdx.x;          // 0..255
  const int xcd = lin & 7;
  const int jslot = lin >> 3;               // 0..31
  const int b = xcd >> 1;                   // batch pinned to an XCD pair
  const int slot = (xcd & 1) * 32 + jslot;  // 0..63
  const int pp = slot >> 2;                 // pair index 0..15
  const int h = slot & 3;                   // split 0..3
  const size_t bS = (size_t)b * S_LEN;

  int4_ kreg[4], vreg[4];
  const int crow = t >> 5;        // 0..15: this thread owns key-rows crow*4 .. crow*4+3
  const int cd8 = (t & 31) << 3;  // d chunk start
  const int vko = (crow & 3) * 32 + (crow >> 2) * 8;  // [g][s] byte offset of this thread's 4 keys

#define LOAD_TILE(T0)                                                              \
  do {                                                                             \
    const size_t kb_ = bS + (size_t)((T0)*64);                                     \
    _Pragma("unroll") for (int i_ = 0; i_ < 4; ++i_) {                             \
      kreg[i_] = *(const int4_*)(Kb + (kb_ + crow * 4 + i_) * D_DIM + cd8);        \
      vreg[i_] = *(const int4_*)(Vb + (kb_ + crow * 4 + i_) * D_DIM + cd8);        \
    }                                                                              \
  } while (0)

#define STORE_TILE(BUF)                                                            \
  do {                                                                             \
    unsigned char* bK_ = (BUF);                                                    \
    unsigned char* bV_ = (BUF) + 32768;                                            \
    _Pragma("unroll") for (int i_ = 0; i_ < 4; ++i_) {                             \
      const int row_ = crow * 4 + i_;                                              \
      *(int4_*)&bK_[row_ * 512 + ((cd8 * 2) ^ ((row_ & 7) << 4))] = kreg[i_];      \
    }                                                                              \
    const unsigned short* v0_ = (const unsigned short*)&vreg[0];                   \
    const unsigned short* v1_ = (const unsigned short*)&vreg[1];                   \
    const unsigned short* v2_ = (const unsigned short*)&vreg[2];                   \
    const unsigned short* v3_ = (const unsigned short*)&vreg[3];                   \
    _Pragma("unroll") for (int jj_ = 0; jj_ < 8; ++jj_) {                          \
      const int d_ = cd8 + jj_;                                                    \
      const int sw_ = ((d_ ^ (d_ >> 4)) & 14) << 3;                                \
      short4_ pv_;                                                                 \
      pv_[0] = (short)v0_[jj_]; pv_[1] = (short)v1_[jj_];                          \
      pv_[2] = (short)v2_[jj_]; pv_[3] = (short)v3_[jj_];                          \
      *(short4_*)&bV_[d_ * 128 + (vko ^ sw_)] = pv_;                               \
    }                                                                              \
  } while (0)

  for (int ci = 0; ci < 2; ++ci) {
    const int qc = ci ? (31 - pp) : pp;
    const int last = 2 * qc + 1;
    const int qrow0 = qc * 128;
    const int q_g = qrow0 + w * 16 + lm;

    // Q fragments (B-operand of swapped QK^T): q = lm, k-chunk = ch*32 + g*8 + j
    short8 qf[8];
    {
      const unsigned short* qp = Qb + (bS + (size_t)(qrow0 + w * 16 + lm)) * D_DIM + g * 8;
#pragma unroll
      for (int ch = 0; ch < 8; ++ch) qf[ch] = *(const short8*)(qp + ch * 32);
    }

    f32x4 o[16];
#pragma unroll
    for (int dt = 0; dt < 16; ++dt) o[dt] = (f32x4){0.f, 0.f, 0.f, 0.f};
    float mrun = -1e30f, lrun = 0.f;

    // prologue: stage tile h into buf0; prefetch tile h+4 into regs
    if (h <= last) {
      LOAD_TILE(h);
      STORE_TILE(sBuf[0]);
      if (h + 4 <= last) LOAD_TILE(h + 4);
    }
    __syncthreads();

    int p = 0;
    for (int tt = h; tt <= last; tt += 4) {
      const int k0 = tt * 64;
      const unsigned char* bK = sBuf[p];
      const unsigned char* bV = sBuf[p] + 32768;

      // stage NEXT tile from regs, then issue loads for the one after (land during compute)
      if (tt + 4 <= last) {
        STORE_TILE(sBuf[p ^ 1]);
        if (tt + 8 <= last) LOAD_TILE(tt + 8);
      }

      // ---- QK^T (S^T = K * Q^T): C col = q (lm), C row = key-in-16 (g*4+r) ----
      f32x4 sacc[4];
#pragma unroll
      for (int s = 0; s < 4; ++s) sacc[s] = (f32x4){0.f, 0.f, 0.f, 0.f};
      __builtin_amdgcn_s_setprio(1);
#pragma unroll
      for (int ch = 0; ch < 8; ++ch) {
#pragma unroll
        for (int s = 0; s < 4; ++s) {
          const int key = s * 16 + lm;
          const int off = key * 512 + (((ch * 32 + g * 8) * 2) ^ ((key & 7) << 4));
          short8 kf = *(const short8*)&bK[off];
          sacc[s] = __builtin_amdgcn_mfma_f32_16x16x32_bf16(kf, qf[ch], sacc[s], 0, 0, 0);
        }
      }
      __builtin_amdgcn_s_setprio(0);

      // ---- online softmax (stats per q = lm, replicated across 4 lane groups) ----
      float sv[4][4];
      float tmax = -1e30f;
      const bool fastm = tflags[b * 64 + tt] && (k0 + 63 <= qrow0 + w * 16);
      if (fastm) {
#pragma unroll
        for (int s = 0; s < 4; ++s)
#pragma unroll
          for (int r = 0; r < 4; ++r) {
            sv[s][r] = sacc[s][r];
            tmax = fmaxf(tmax, sacc[s][r]);
          }
      } else {
#pragma unroll
        for (int s = 0; s < 4; ++s) {
          const int4_ mw = *(const int4_*)(amask + bS + k0 + s * 16 + g * 4);
#pragma unroll
          for (int r = 0; r < 4; ++r) {
            const int key_g = k0 + s * 16 + g * 4 + r;
            const bool ok = (key_g <= q_g) && (mw[r] != 0);
            const float x = ok ? sacc[s][r] : -1e30f;
            sv[s][r] = x;
            tmax = fmaxf(tmax, x);
          }
        }
      }
      tmax = fmaxf(tmax, __shfl_xor(tmax, 16));
      tmax = fmaxf(tmax, __shfl_xor(tmax, 32));

      // defer-rescale (T13, THR=8): rescale only when some row's max grew by > 8.
      // While deferred, P = exp(s - m_old) <= e^8; l tracks the same reference, so
      // partial/l and the cross-split combine are unchanged (bf16 error is relative).
      if (__ballot(tmax > mrun + 8.0f)) {
        const float mnew = fmaxf(mrun, tmax);
        const float corr = __builtin_amdgcn_exp2f((mrun - mnew) * 1.44269504f);
        mrun = mnew;
        lrun *= corr;
        float cr[4];
#pragma unroll
        for (int r = 0; r < 4; ++r) cr[r] = __shfl(corr, g * 4 + r);
#pragma unroll
        for (int dt = 0; dt < 16; ++dt)
#pragma unroll
          for (int r = 0; r < 4; ++r) o[dt][r] *= cr[r];
      }

      float psum = 0.f;
      short4_ pk[4];
#pragma unroll
      for (int s = 0; s < 4; ++s) {
#pragma unroll
        for (int r = 0; r < 4; ++r) {
          const float p_ = __builtin_amdgcn_exp2f((sv[s][r] - mrun) * 1.44269504f);
          psum += p_;
          pk[s][r] = (short)f2bf(p_);
        }
      }
      psum += __shfl_xor(psum, 16);
      psum += __shfl_xor(psum, 32);
      lrun += psum;

      // ---- PV: A = P (in-lane), B = V^T via 2x b128 reads per dt ([g][s] layout) ----
      __builtin_amdgcn_s_setprio(1);
#pragma unroll
      for (int dt = 0; dt < 16; ++dt) {
        const int d = dt * 16 + lm;
        const int sw = ((d ^ (d >> 4)) & 14) << 3;
        const unsigned char* vr = &bV[d * 128];
        short8 v01 = *(const short8*)&vr[(g * 32) ^ sw];
        short8 v23 = *(const short8*)&vr[(g * 32 + 16) ^ sw];
        short4_ f0 = {v01[0], v01[1], v01[2], v01[3]};
        short4_ f1 = {v01[4], v01[5], v01[6], v01[7]};
        short4_ f2 = {v23[0], v23[1], v23[2], v23[3]};
        short4_ f3 = {v23[4], v23[5], v23[6], v23[7]};
        o[dt] = MFMA16(pk[0], f0, o[dt]);
        o[dt] = MFMA16(pk[1], f1, o[dt]);
        o[dt] = MFMA16(pk[2], f2, o[dt]);
        o[dt] = MFMA16(pk[3], f3, o[dt]);
      }
      __builtin_amdgcn_s_setprio(0);

      __syncthreads();  // staged STORE visible; all waves done reading bK/bV
      p ^= 1;
    }

    // ---- write unnormalized bf16 partial + stats for this chunk ----
    unsigned short* op =
        Pall + (size_t)h * BSD_TOT + (bS + (size_t)(qrow0 + w * 16)) * D_DIM;
#pragma unroll
    for (int dt = 0; dt < 16; ++dt)
#pragma unroll
      for (int r = 0; r < 4; ++r)
        op[(size_t)(g * 4 + r) * D_DIM + dt * 16 + lm] = f2bf(o[dt][r]);
    if (g == 0) {
      stats[(size_t)h * BS_TOT + bS + q_g] = mrun;
      stats[(size_t)(4 + h) * BS_TOT + bS + q_g] = lrun;
    }
  }
#undef LOAD_TILE
#undef STORE_TILE
}

// ---------------- Combine 4 bf16 partials -> f32 output ----------------
__global__ __launch_bounds__(256)
void combine4_kernel(float* __restrict__ Out, const unsigned short* __restrict__ Pall,
                     const float* __restrict__ stats) {
  const int idx = (int)blockIdx.x * 256 + (int)threadIdx.x;  // one f32x4 / 4 bf16
  const int row = idx >> 6;
  const float m0 = stats[row];
  const float m1 = stats[BS_TOT + row];
  const float m2 = stats[2 * BS_TOT + row];
  const float m3 = stats[3 * BS_TOT + row];
  const float mm = fmaxf(fmaxf(m0, m1), fmaxf(m2, m3));
  const float s0 = __builtin_amdgcn_exp2f((m0 - mm) * 1.44269504f);
  const float s1 = __builtin_amdgcn_exp2f((m1 - mm) * 1.44269504f);
  const float s2 = __builtin_amdgcn_exp2f((m2 - mm) * 1.44269504f);
  const float s3 = __builtin_amdgcn_exp2f((m3 - mm) * 1.44269504f);
  const float denom = s0 * stats[4 * BS_TOT + row] + s1 * stats[5 * BS_TOT + row] +
                      s2 * stats[6 * BS_TOT + row] + s3 * stats[7 * BS_TOT + row];
  const float inv = 1.f / denom;

  ushort4_ u0 = *(const ushort4_*)(Pall + (size_t)idx * 4);
  ushort4_ u1 = *(const ushort4_*)(Pall + BSD_TOT + (size_t)idx * 4);
  ushort4_ u2 = *(const ushort4_*)(Pall + 2 * BSD_TOT + (size_t)idx * 4);
  ushort4_ u3 = *(const ushort4_*)(Pall + 3 * BSD_TOT + (size_t)idx * 4);
  f32x4 acc;
#pragma unroll
  for (int j = 0; j < 4; ++j)
    acc[j] = bf2f(u0[j]) * s0 + bf2f(u1[j]) * s1 + bf2f(u2[j]) * s2 + bf2f(u3[j]) * s3;
  *(f32x4*)(Out + (size_t)idx * 4) = acc * inv;
}

// ---------------- Fallback: single-pass attention (round-1, known good) ----------------
__global__ __launch_bounds__(256, 2)
void attn_kernel(const unsigned short* __restrict__ Qb,
                 const unsigned short* __restrict__ Kb,
                 const unsigned short* __restrict__ Vb,
                 const int* __restrict__ amask,
                 float* __restrict__ Out) {
  __shared__ __align__(16) unsigned char sK[32768];
  __shared__ __align__(16) unsigned char sVT[32768];

  const int t = (int)threadIdx.x;
  const int l = t & 63;
  const int w = t >> 6;
  const int lm = l & 15;
  const int g = l >> 4;
  const int b = (int)blockIdx.x >> 6;
  const int qb = (int)blockIdx.x & 63;
  const size_t bS = (size_t)b * S_LEN;

  short8 qf[8];
  {
    const unsigned short* qp = Qb + (bS + (size_t)(qb * 64 + w * 16 + lm)) * D_DIM + g * 8;
#pragma unroll
    for (int ch = 0; ch < 8; ++ch) qf[ch] = *(const short8*)(qp + ch * 32);
  }

  f32x4 o[16];
#pragma unroll
  for (int dt = 0; dt < 16; ++dt) o[dt] = (f32x4){0.f, 0.f, 0.f, 0.f};
  float mrun = -1e30f, lrun = 0.f;
  const int q_g = qb * 64 + w * 16 + lm;

  for (int tt = 0; tt <= qb; ++tt) {
    const int k0 = tt * 64;
#pragma unroll
    for (int i = 0; i < 8; ++i) {
      const int c = t + i * 256;
      const int row = c >> 5;
      const int d8 = (c & 31) << 3;
      {
        int4_ kvv = *(const int4_*)(Kb + (bS + (size_t)(k0 + row)) * D_DIM + d8);
        *(int4_*)&sK[row * 512 + ((d8 * 2) ^ ((row & 7) << 4))] = kvv;
      }
      {
        int4_ vvv = *(const int4_*)(Vb + (bS + (size_t)(k0 + row)) * D_DIM + d8);
        const unsigned short* pv = (const unsigned short*)&vvv;
#pragma unroll
        for (int jj = 0; jj < 8; ++jj) {
          const int d = d8 + jj;
          const int swz = (((d >> 4) ^ d) & 15) << 3;
          *(unsigned short*)&sVT[d * 128 + ((row * 2) ^ swz)] = pv[jj];
        }
      }
    }
    __syncthreads();

    f32x4 sacc[4];
#pragma unroll
    for (int s = 0; s < 4; ++s) sacc[s] = (f32x4){0.f, 0.f, 0.f, 0.f};
#pragma unroll
    for (int ch = 0; ch < 8; ++ch) {
#pragma unroll
      for (int s = 0; s < 4; ++s) {
        const int key = s * 16 + lm;
        const int off = key * 512 + (((ch * 32 + g * 8) * 2) ^ ((key & 7) << 4));
        short8 kf = *(const short8*)&sK[off];
        sacc[s] = __builtin_amdgcn_mfma_f32_16x16x32_bf16(kf, qf[ch], sacc[s], 0, 0, 0);
      }
    }

    float sv[4][4];
    float tmax = -1e30f;
#pragma unroll
    for (int s = 0; s < 4; ++s) {
      const int4_ mw = *(const int4_*)(amask + bS + k0 + s * 16 + g * 4);
#pragma unroll
      for (int r = 0; r < 4; ++r) {
        const int key_g = k0 + s * 16 + g * 4 + r;
        const bool ok = (key_g <= q_g) && (mw[r] != 0);
        const float x = ok ? sacc[s][r] : -1e30f;
        sv[s][r] = x;
        tmax = fmaxf(tmax, x);
      }
    }
    tmax = fmaxf(tmax, __shfl_xor(tmax, 16));
    tmax = fmaxf(tmax, __shfl_xor(tmax, 32));
    const float mnew = fmaxf(mrun, tmax);
    const float corr = __builtin_amdgcn_exp2f((mrun - mnew) * 1.44269504f);
    mrun = mnew;

    float psum = 0.f;
    short4_ pk[4];
#pragma unroll
    for (int s = 0; s < 4; ++s) {
#pragma unroll
      for (int r = 0; r < 4; ++r) {
        const float p = __builtin_amdgcn_exp2f((sv[s][r] - mnew) * 1.44269504f);
        psum += p;
        pk[s][r] = (short)f2bf(p);
      }
    }
    psum += __shfl_xor(psum, 16);
    psum += __shfl_xor(psum, 32);
    lrun = lrun * corr + psum;

    float cr[4];
#pragma unroll
    for (int r = 0; r < 4; ++r) cr[r] = __shfl(corr, g * 4 + r);
#pragma unroll
    for (int dt = 0; dt < 16; ++dt)
#pragma unroll
      for (int r = 0; r < 4; ++r) o[dt][r] *= cr[r];

#pragma unroll
    for (int dt = 0; dt < 16; ++dt) {
      const int d = dt * 16 + lm;
      const int swz = (((d >> 4) ^ d) & 15) << 3;
#pragma unroll
      for (int s = 0; s < 4; ++s) {
        short4_ vf = *(const short4_*)&sVT[d * 128 + ((s * 32 + g * 8) ^ swz)];
        o[dt] = MFMA16(pk[s], vf, o[dt]);
      }
    }
    __syncthreads();
  }

  const float inv = 1.f / lrun;
  float ir[4];
#pragma unroll
  for (int r = 0; r < 4; ++r) ir[r] = __shfl(inv, g * 4 + r);
  float* op = Out + (bS + (size_t)(qb * 64 + w * 16)) * D_DIM;
#pragma unroll
  for (int dt = 0; dt < 16; ++dt)
#pragma unroll
    for (int r = 0; r < 4; ++r)
      op[(size_t)(g * 4 + r) * D_DIM + dt * 16 + lm] = o[dt][r] * ir[r];
}

extern "C" void kernel_launch(void* const* d_in, const int* in_sizes, int n_in,
                              void* d_out, int out_size, void* d_ws, size_t ws_size,
                              hipStream_t stream) {
  const float* x_q = (const float*)d_in[0];
  const float* x_k = (const float*)d_in[1];
  const float* x_v = (const float*)d_in[2];
  const int* amask = (const int*)d_in[3];
  const float* Wq = (const float*)d_in[4];
  const float* Wk = (const float*)d_in[5];
  const float* Wv = (const float*)d_in[6];

  unsigned short* Qb = (unsigned short*)d_ws;
  unsigned short* Kb = Qb + BSD_TOT;
  unsigned short* Vb = Kb + BSD_TOT;

  const size_t qkv_bytes = 3 * BSD_TOT * sizeof(unsigned short);   // 25.2 MB
  const size_t pall_bytes = 4 * BSD_TOT * sizeof(unsigned short);  // 33.6 MB
  const size_t stat_bytes = 8 * (size_t)BS_TOT * sizeof(float);    // 512 KB
  const size_t flag_bytes = (size_t)B_N * 64 * sizeof(int);        // 1 KB
  if (ws_size >= qkv_bytes + pall_bytes + stat_bytes + flag_bytes) {
    unsigned short* Pall = (unsigned short*)((char*)d_ws + qkv_bytes);
    float* stats = (float*)((char*)d_ws + qkv_bytes + pall_bytes);
    int* tflags = (int*)((char*)d_ws + qkv_bytes + pall_bytes + stat_bytes);
    dim3 pg(128, 2, 3);
    proj_kernel<<<pg, dim3(256), 0, stream>>>(x_q, x_k, x_v, Wq, Wk, Wv, Qb, Kb, Vb,
                                              amask, tflags);
    attn_split4_kernel<<<dim3(256), dim3(512), 0, stream>>>(
        Qb, Kb, Vb, amask, tflags, Pall, stats);
    combine4_kernel<<<dim3((unsigned)(BSD_TOT / 4 / 256)), dim3(256), 0, stream>>>(
        (float*)d_out, Pall, stats);
  } else {
    dim3 pg(128, 2, 3);
    proj_kernel<<<pg, dim3(256), 0, stream>>>(x_q, x_k, x_v, Wq, Wk, Wv, Qb, Kb, Vb,
                                              amask, (int*)((char*)d_ws + qkv_bytes));
    attn_kernel<<<dim3(B_N * (S_LEN / 64)), dim3(256), 0, stream>>>(Qb, Kb, Vb, amask,
                                                                    (float*)d_out);
  }
}

// Round 18
// 95.397 us; speedup vs baseline: 2.9558x; 1.0024x over previous
//
#include <hip/hip_runtime.h>

#define B_N 4
#define S_LEN 4096
#define D_DIM 256
#define BS_TOT (B_N * S_LEN)
#define BSD_TOT ((size_t)BS_TOT * D_DIM)

typedef __attribute__((ext_vector_type(8))) short short8;
typedef __attribute__((ext_vector_type(4))) short short4_;
typedef __attribute__((ext_vector_type(4))) unsigned short ushort4_;
typedef __attribute__((ext_vector_type(4))) float f32x4;
typedef __attribute__((ext_vector_type(4))) int int4_;

static __device__ __forceinline__ unsigned short f2bf(float f) {
  unsigned u = __builtin_bit_cast(unsigned, f);
  u += 0x7fffu + ((u >> 16) & 1u);
  return (unsigned short)(u >> 16);
}
static __device__ __forceinline__ float bf2f(unsigned short h) {
  unsigned u = ((unsigned)h) << 16;
  return __builtin_bit_cast(float, u);
}

#if __has_builtin(__builtin_amdgcn_mfma_f32_16x16x16bf16_1k)
#define MFMA16(a, b, c) __builtin_amdgcn_mfma_f32_16x16x16bf16_1k((a), (b), (c), 0, 0, 0)
#else
static __device__ __forceinline__ f32x4 mfma16_asm(short4_ a, short4_ b, f32x4 c) {
  asm volatile("v_mfma_f32_16x16x16_bf16 %0, %1, %2, %0" : "+v"(c) : "v"(a), "v"(b));
  return c;
}
#define MFMA16(a, b, c) mfma16_asm((a), (b), (c))
#endif

// ---------------- Projection: Out[m][n] = sum_k X[m][k] * W[n][k]  (bf16 out) ----------------
// 1-D grid of 768, XCD-aware decode: the two N-halves of an M-tile are consecutive j on the
// SAME XCD -> second block's X reads hit L2. Side job: 4 blocks compute per-tile mask flags.
__global__ __launch_bounds__(256, 2)
void proj_kernel(const float* __restrict__ X0, const float* __restrict__ X1,
                 const float* __restrict__ X2,
                 const float* __restrict__ W0, const float* __restrict__ W1,
                 const float* __restrict__ W2,
                 unsigned short* __restrict__ O0, unsigned short* __restrict__ O1,
                 unsigned short* __restrict__ O2,
                 const int* __restrict__ amask, int* __restrict__ flags) {
  __shared__ __align__(16) unsigned char sA[16384];
  __shared__ __align__(16) unsigned char sB[16384];

  const int lin = (int)blockIdx.x;  // 0..767
  const int xcd = lin & 7;
  const int j = lin >> 3;       // 0..95
  const int z = j >> 5;         // matrix 0..2 (32 j per z per xcd)
  const int rem = j & 31;       // 0..31
  const int mt = xcd * 16 + (rem >> 1);  // M-tile 0..127
  const int nt = rem & 1;                // N-tile 0..1

  const float* X = (z == 0) ? X0 : (z == 1) ? X1 : X2;
  const float* W = (z == 0) ? W0 : (z == 1) ? W1 : W2;
  unsigned short* O = (z == 0) ? O0 : (z == 1) ? O1 : O2;
  const float mult = (z == 0) ? 0.0625f : 1.0f;  // fold 1/sqrt(D) into Q

  const int t = (int)threadIdx.x;
  const int l = t & 63, w = t >> 6;
  const int lm = l & 15, g = l >> 4;
  const int wr = w >> 1, wc = w & 1;
  const int mb = mt * 128;
  const int nb = nt * 128;

  // side job: mask flags (first 4 blocks of the grid: xcd=lin, j=0 -> z=0,mt=xcd*16,nt=0)
  if (lin < B_N && t < 64) {
    const int4_* p = (const int4_*)(amask + ((size_t)lin * 64 + t) * 64);
    int all1 = 1;
#pragma unroll
    for (int i = 0; i < 16; ++i) {
      int4_ v = p[i];
      all1 &= (v[0] != 0) & (v[1] != 0) & (v[2] != 0) & (v[3] != 0);
    }
    flags[lin * 64 + t] = all1;
  }

  f32x4 acc[4][4];
#pragma unroll
  for (int i = 0; i < 4; ++i)
#pragma unroll
    for (int j2 = 0; j2 < 4; ++j2) acc[i][j2] = (f32x4){0.f, 0.f, 0.f, 0.f};

  for (int ks = 0; ks < 4; ++ks) {
    const int k0 = ks * 64;
#pragma unroll
    for (int i = 0; i < 4; ++i) {
      const int c = t + i * 256;
      const int row = c >> 3;
      const int kc = (c & 7) * 8;
      const float* xp = X + (size_t)(mb + row) * D_DIM + k0 + kc;
      const float* wp = W + (size_t)(nb + row) * D_DIM + k0 + kc;
      f32x4 x0 = *(const f32x4*)xp;
      f32x4 x1 = *(const f32x4*)(xp + 4);
      f32x4 w0 = *(const f32x4*)wp;
      f32x4 w1 = *(const f32x4*)(wp + 4);
      short8 xa, wa;
#pragma unroll
      for (int jj = 0; jj < 4; ++jj) {
        xa[jj] = (short)f2bf(x0[jj]);
        xa[jj + 4] = (short)f2bf(x1[jj]);
        wa[jj] = (short)f2bf(w0[jj]);
        wa[jj + 4] = (short)f2bf(w1[jj]);
      }
      const int off = row * 128 + ((kc * 2) ^ ((row & 7) << 4));
      *(short8*)&sA[off] = xa;
      *(short8*)&sB[off] = wa;
    }
    __syncthreads();
#pragma unroll
    for (int kk = 0; kk < 2; ++kk) {
      short8 af[4], bg[4];
#pragma unroll
      for (int mi = 0; mi < 4; ++mi) {
        const int row = wr * 64 + mi * 16 + lm;
        af[mi] = *(const short8*)&sA[row * 128 + (((kk * 32 + g * 8) * 2) ^ ((row & 7) << 4))];
      }
#pragma unroll
      for (int ni = 0; ni < 4; ++ni) {
        const int row = wc * 64 + ni * 16 + lm;
        bg[ni] = *(const short8*)&sB[row * 128 + (((kk * 32 + g * 8) * 2) ^ ((row & 7) << 4))];
      }
#pragma unroll
      for (int mi = 0; mi < 4; ++mi)
#pragma unroll
        for (int ni = 0; ni < 4; ++ni)
          acc[mi][ni] = __builtin_amdgcn_mfma_f32_16x16x32_bf16(af[mi], bg[ni], acc[mi][ni], 0, 0, 0);
    }
    __syncthreads();
  }

#pragma unroll
  for (int mi = 0; mi < 4; ++mi)
#pragma unroll
    for (int ni = 0; ni < 4; ++ni)
#pragma unroll
      for (int r = 0; r < 4; ++r) {
        const int mg = mb + wr * 64 + mi * 16 + g * 4 + r;
        const int ng = nb + wc * 64 + ni * 16 + lm;
        O[(size_t)mg * D_DIM + ng] = f2bf(acc[mi][ni][r] * mult);
      }
}

// ---------------- Flash attention: QBLK=128, chunk-pair per block, split-4, XCD-local blocks ----------------
// V^T LDS row layout: within each 128B d-row, key k = s*16+g*4+r lives at byte g*32 + s*8 + r*2,
// XOR-swizzled at 16B granule by ((d^(d>>4))&14)<<3. PV reads 2x b128 per (dt): s={0,1} and s={2,3}.
// Defer-rescale THR=8 (T13).
__global__ __launch_bounds__(512, 2)
void attn_split4_kernel(const unsigned short* __restrict__ Qb,
                        const unsigned short* __restrict__ Kb,
                        const unsigned short* __restrict__ Vb,
                        const int* __restrict__ amask,
                        const int* __restrict__ tflags,
                        unsigned short* __restrict__ Pall,  // 4 bf16 partials [h][B*S][D]
                        float* __restrict__ stats)          // m[4][B*S], l[4][B*S]
{
  // per buffer: K at [0,32768), V^T at [32768,65536)
  __shared__ __align__(16) unsigned char sBuf[2][65536];

  const int t = (int)threadIdx.x;
  const int l = t & 63;
  const int w = t >> 6;  // 0..7
  const int lm = l & 15;
  const int g = l >> 4;

  const int lin = (int)blockIdx.x;          // 0..255
  const int xcd = lin & 7;
  const int jslot = lin >> 3;               // 0..31
  const int b = xcd >> 1;                   // batch pinned to an XCD pair
  const int slot = (xcd & 1) * 32 + jslot;  // 0..63
  const int pp = slot >> 2;                 // pair index 0..15
  const int h = slot & 3;                   // split 0..3
  const size_t bS = (size_t)b * S_LEN;

  int4_ kreg[4], vreg[4];
  const int crow = t >> 5;        // 0..15: this thread owns key-rows crow*4 .. crow*4+3
  const int cd8 = (t & 31) << 3;  // d chunk start
  const int vko = (crow & 3) * 32 + (crow >> 2) * 8;  // [g][s] byte offset of this thread's 4 keys

#define LOAD_TILE(T0)                                                              \
  do {                                                                             \
    const size_t kb_ = bS + (size_t)((T0)*64);                                     \
    _Pragma("unroll") for (int i_ = 0; i_ < 4; ++i_) {                             \
      kreg[i_] = *(const int4_*)(Kb + (kb_ + crow * 4 + i_) * D_DIM + cd8);        \
      vreg[i_] = *(const int4_*)(Vb + (kb_ + crow * 4 + i_) * D_DIM + cd8);        \
    }                                                                              \
  } while (0)

#define STORE_TILE(BUF)                                                            \
  do {                                                                             \
    unsigned char* bK_ = (BUF);                                                    \
    unsigned char* bV_ = (BUF) + 32768;                                            \
    _Pragma("unroll") for (int i_ = 0; i_ < 4; ++i_) {                             \
      const int row_ = crow * 4 + i_;                                              \
      *(int4_*)&bK_[row_ * 512 + ((cd8 * 2) ^ ((row_ & 7) << 4))] = kreg[i_];      \
    }                                                                              \
    const unsigned short* v0_ = (const unsigned short*)&vreg[0];                   \
    const unsigned short* v1_ = (const unsigned short*)&vreg[1];                   \
    const unsigned short* v2_ = (const unsigned short*)&vreg[2];                   \
    const unsigned short* v3_ = (const unsigned short*)&vreg[3];                   \
    _Pragma("unroll") for (int jj_ = 0; jj_ < 8; ++jj_) {                          \
      const int d_ = cd8 + jj_;                                                    \
      const int sw_ = ((d_ ^ (d_ >> 4)) & 14) << 3;                                \
      short4_ pv_;                                                                 \
      pv_[0] = (short)v0_[jj_]; pv_[1] = (short)v1_[jj_];                          \
      pv_[2] = (short)v2_[jj_]; pv_[3] = (short)v3_[jj_];                          \
      *(short4_*)&bV_[d_ * 128 + (vko ^ sw_)] = pv_;                               \
    }                                                                              \
  } while (0)

  for (int ci = 0; ci < 2; ++ci) {
    const int qc = ci ? (31 - pp) : pp;
    const int last = 2 * qc + 1;
    const int qrow0 = qc * 128;
    const int q_g = qrow0 + w * 16 + lm;

    // Q fragments (B-operand of swapped QK^T): q = lm, k-chunk = ch*32 + g*8 + j
    short8 qf[8];
    {
      const unsigned short* qp = Qb + (bS + (size_t)(qrow0 + w * 16 + lm)) * D_DIM + g * 8;
#pragma unroll
      for (int ch = 0; ch < 8; ++ch) qf[ch] = *(const short8*)(qp + ch * 32);
    }

    f32x4 o[16];
#pragma unroll
    for (int dt = 0; dt < 16; ++dt) o[dt] = (f32x4){0.f, 0.f, 0.f, 0.f};
    float mrun = -1e30f, lrun = 0.f;

    // prologue: stage tile h into buf0; prefetch tile h+4 into regs
    if (h <= last) {
      LOAD_TILE(h);
      STORE_TILE(sBuf[0]);
      if (h + 4 <= last) LOAD_TILE(h + 4);
    }
    __syncthreads();

    int p = 0;
    for (int tt = h; tt <= last; tt += 4) {
      const int k0 = tt * 64;
      const unsigned char* bK = sBuf[p];
      const unsigned char* bV = sBuf[p] + 32768;

      // stage NEXT tile from regs, then issue loads for the one after (land during compute)
      if (tt + 4 <= last) {
        STORE_TILE(sBuf[p ^ 1]);
        if (tt + 8 <= last) LOAD_TILE(tt + 8);
      }

      // ---- QK^T (S^T = K * Q^T): C col = q (lm), C row = key-in-16 (g*4+r) ----
      f32x4 sacc[4];
#pragma unroll
      for (int s = 0; s < 4; ++s) sacc[s] = (f32x4){0.f, 0.f, 0.f, 0.f};
      __builtin_amdgcn_s_setprio(1);
#pragma unroll
      for (int ch = 0; ch < 8; ++ch) {
#pragma unroll
        for (int s = 0; s < 4; ++s) {
          const int key = s * 16 + lm;
          const int off = key * 512 + (((ch * 32 + g * 8) * 2) ^ ((key & 7) << 4));
          short8 kf = *(const short8*)&bK[off];
          sacc[s] = __builtin_amdgcn_mfma_f32_16x16x32_bf16(kf, qf[ch], sacc[s], 0, 0, 0);
        }
      }
      __builtin_amdgcn_s_setprio(0);

      // ---- online softmax (stats per q = lm, replicated across 4 lane groups) ----
      float sv[4][4];
      float tmax = -1e30f;
      const bool fastm = tflags[b * 64 + tt] && (k0 + 63 <= qrow0 + w * 16);
      if (fastm) {
#pragma unroll
        for (int s = 0; s < 4; ++s)
#pragma unroll
          for (int r = 0; r < 4; ++r) {
            sv[s][r] = sacc[s][r];
            tmax = fmaxf(tmax, sacc[s][r]);
          }
      } else {
#pragma unroll
        for (int s = 0; s < 4; ++s) {
          const int4_ mw = *(const int4_*)(amask + bS + k0 + s * 16 + g * 4);
#pragma unroll
          for (int r = 0; r < 4; ++r) {
            const int key_g = k0 + s * 16 + g * 4 + r;
            const bool ok = (key_g <= q_g) && (mw[r] != 0);
            const float x = ok ? sacc[s][r] : -1e30f;
            sv[s][r] = x;
            tmax = fmaxf(tmax, x);
          }
        }
      }
      tmax = fmaxf(tmax, __shfl_xor(tmax, 16));
      tmax = fmaxf(tmax, __shfl_xor(tmax, 32));

      // defer-rescale (T13, THR=8)
      if (__ballot(tmax > mrun + 8.0f)) {
        const float mnew = fmaxf(mrun, tmax);
        const float corr = __builtin_amdgcn_exp2f((mrun - mnew) * 1.44269504f);
        mrun = mnew;
        lrun *= corr;
        float cr[4];
#pragma unroll
        for (int r = 0; r < 4; ++r) cr[r] = __shfl(corr, g * 4 + r);
#pragma unroll
        for (int dt = 0; dt < 16; ++dt)
#pragma unroll
          for (int r = 0; r < 4; ++r) o[dt][r] *= cr[r];
      }

      float psum = 0.f;
      short4_ pk[4];
#pragma unroll
      for (int s = 0; s < 4; ++s) {
#pragma unroll
        for (int r = 0; r < 4; ++r) {
          const float p_ = __builtin_amdgcn_exp2f((sv[s][r] - mrun) * 1.44269504f);
          psum += p_;
          pk[s][r] = (short)f2bf(p_);
        }
      }
      psum += __shfl_xor(psum, 16);
      psum += __shfl_xor(psum, 32);
      lrun += psum;

      // ---- PV: A = P (in-lane), B = V^T via 2x b128 reads per dt ([g][s] layout) ----
      __builtin_amdgcn_s_setprio(1);
#pragma unroll
      for (int dt = 0; dt < 16; ++dt) {
        const int d = dt * 16 + lm;
        const int sw = ((d ^ (d >> 4)) & 14) << 3;
        const unsigned char* vr = &bV[d * 128];
        short8 v01 = *(const short8*)&vr[(g * 32) ^ sw];
        short8 v23 = *(const short8*)&vr[(g * 32 + 16) ^ sw];
        short4_ f0 = {v01[0], v01[1], v01[2], v01[3]};
        short4_ f1 = {v01[4], v01[5], v01[6], v01[7]};
        short4_ f2 = {v23[0], v23[1], v23[2], v23[3]};
        short4_ f3 = {v23[4], v23[5], v23[6], v23[7]};
        o[dt] = MFMA16(pk[0], f0, o[dt]);
        o[dt] = MFMA16(pk[1], f1, o[dt]);
        o[dt] = MFMA16(pk[2], f2, o[dt]);
        o[dt] = MFMA16(pk[3], f3, o[dt]);
      }
      __builtin_amdgcn_s_setprio(0);

      __syncthreads();  // staged STORE visible; all waves done reading bK/bV
      p ^= 1;
    }

    // ---- write unnormalized bf16 partial + stats for this chunk ----
    unsigned short* op =
        Pall + (size_t)h * BSD_TOT + (bS + (size_t)(qrow0 + w * 16)) * D_DIM;
#pragma unroll
    for (int dt = 0; dt < 16; ++dt)
#pragma unroll
      for (int r = 0; r < 4; ++r)
        op[(size_t)(g * 4 + r) * D_DIM + dt * 16 + lm] = f2bf(o[dt][r]);
    if (g == 0) {
      stats[(size_t)h * BS_TOT + bS + q_g] = mrun;
      stats[(size_t)(4 + h) * BS_TOT + bS + q_g] = lrun;
    }
  }
#undef LOAD_TILE
#undef STORE_TILE
}

// ---------------- Combine 4 bf16 partials -> f32 output ----------------
__global__ __launch_bounds__(256)
void combine4_kernel(float* __restrict__ Out, const unsigned short* __restrict__ Pall,
                     const float* __restrict__ stats) {
  const int idx = (int)blockIdx.x * 256 + (int)threadIdx.x;  // one f32x4 / 4 bf16
  const int row = idx >> 6;
  const float m0 = stats[row];
  const float m1 = stats[BS_TOT + row];
  const float m2 = stats[2 * BS_TOT + row];
  const float m3 = stats[3 * BS_TOT + row];
  const float mm = fmaxf(fmaxf(m0, m1), fmaxf(m2, m3));
  const float s0 = __builtin_amdgcn_exp2f((m0 - mm) * 1.44269504f);
  const float s1 = __builtin_amdgcn_exp2f((m1 - mm) * 1.44269504f);
  const float s2 = __builtin_amdgcn_exp2f((m2 - mm) * 1.44269504f);
  const float s3 = __builtin_amdgcn_exp2f((m3 - mm) * 1.44269504f);
  const float denom = s0 * stats[4 * BS_TOT + row] + s1 * stats[5 * BS_TOT + row] +
                      s2 * stats[6 * BS_TOT + row] + s3 * stats[7 * BS_TOT + row];
  const float inv = 1.f / denom;

  ushort4_ u0 = *(const ushort4_*)(Pall + (size_t)idx * 4);
  ushort4_ u1 = *(const ushort4_*)(Pall + BSD_TOT + (size_t)idx * 4);
  ushort4_ u2 = *(const ushort4_*)(Pall + 2 * BSD_TOT + (size_t)idx * 4);
  ushort4_ u3 = *(const ushort4_*)(Pall + 3 * BSD_TOT + (size_t)idx * 4);
  f32x4 acc;
#pragma unroll
  for (int j = 0; j < 4; ++j)
    acc[j] = bf2f(u0[j]) * s0 + bf2f(u1[j]) * s1 + bf2f(u2[j]) * s2 + bf2f(u3[j]) * s3;
  *(f32x4*)(Out + (size_t)idx * 4) = acc * inv;
}

// ---------------- Fallback: single-pass attention (round-1, known good) ----------------
__global__ __launch_bounds__(256, 2)
void attn_kernel(const unsigned short* __restrict__ Qb,
                 const unsigned short* __restrict__ Kb,
                 const unsigned short* __restrict__ Vb,
                 const int* __restrict__ amask,
                 float* __restrict__ Out) {
  __shared__ __align__(16) unsigned char sK[32768];
  __shared__ __align__(16) unsigned char sVT[32768];

  const int t = (int)threadIdx.x;
  const int l = t & 63;
  const int w = t >> 6;
  const int lm = l & 15;
  const int g = l >> 4;
  const int b = (int)blockIdx.x >> 6;
  const int qb = (int)blockIdx.x & 63;
  const size_t bS = (size_t)b * S_LEN;

  short8 qf[8];
  {
    const unsigned short* qp = Qb + (bS + (size_t)(qb * 64 + w * 16 + lm)) * D_DIM + g * 8;
#pragma unroll
    for (int ch = 0; ch < 8; ++ch) qf[ch] = *(const short8*)(qp + ch * 32);
  }

  f32x4 o[16];
#pragma unroll
  for (int dt = 0; dt < 16; ++dt) o[dt] = (f32x4){0.f, 0.f, 0.f, 0.f};
  float mrun = -1e30f, lrun = 0.f;
  const int q_g = qb * 64 + w * 16 + lm;

  for (int tt = 0; tt <= qb; ++tt) {
    const int k0 = tt * 64;
#pragma unroll
    for (int i = 0; i < 8; ++i) {
      const int c = t + i * 256;
      const int row = c >> 5;
      const int d8 = (c & 31) << 3;
      {
        int4_ kvv = *(const int4_*)(Kb + (bS + (size_t)(k0 + row)) * D_DIM + d8);
        *(int4_*)&sK[row * 512 + ((d8 * 2) ^ ((row & 7) << 4))] = kvv;
      }
      {
        int4_ vvv = *(const int4_*)(Vb + (bS + (size_t)(k0 + row)) * D_DIM + d8);
        const unsigned short* pv = (const unsigned short*)&vvv;
#pragma unroll
        for (int jj = 0; jj < 8; ++jj) {
          const int d = d8 + jj;
          const int swz = (((d >> 4) ^ d) & 15) << 3;
          *(unsigned short*)&sVT[d * 128 + ((row * 2) ^ swz)] = pv[jj];
        }
      }
    }
    __syncthreads();

    f32x4 sacc[4];
#pragma unroll
    for (int s = 0; s < 4; ++s) sacc[s] = (f32x4){0.f, 0.f, 0.f, 0.f};
#pragma unroll
    for (int ch = 0; ch < 8; ++ch) {
#pragma unroll
      for (int s = 0; s < 4; ++s) {
        const int key = s * 16 + lm;
        const int off = key * 512 + (((ch * 32 + g * 8) * 2) ^ ((key & 7) << 4));
        short8 kf = *(const short8*)&sK[off];
        sacc[s] = __builtin_amdgcn_mfma_f32_16x16x32_bf16(kf, qf[ch], sacc[s], 0, 0, 0);
      }
    }

    float sv[4][4];
    float tmax = -1e30f;
#pragma unroll
    for (int s = 0; s < 4; ++s) {
      const int4_ mw = *(const int4_*)(amask + bS + k0 + s * 16 + g * 4);
#pragma unroll
      for (int r = 0; r < 4; ++r) {
        const int key_g = k0 + s * 16 + g * 4 + r;
        const bool ok = (key_g <= q_g) && (mw[r] != 0);
        const float x = ok ? sacc[s][r] : -1e30f;
        sv[s][r] = x;
        tmax = fmaxf(tmax, x);
      }
    }
    tmax = fmaxf(tmax, __shfl_xor(tmax, 16));
    tmax = fmaxf(tmax, __shfl_xor(tmax, 32));
    const float mnew = fmaxf(mrun, tmax);
    const float corr = __builtin_amdgcn_exp2f((mrun - mnew) * 1.44269504f);
    mrun = mnew;

    float psum = 0.f;
    short4_ pk[4];
#pragma unroll
    for (int s = 0; s < 4; ++s) {
#pragma unroll
      for (int r = 0; r < 4; ++r) {
        const float p = __builtin_amdgcn_exp2f((sv[s][r] - mnew) * 1.44269504f);
        psum += p;
        pk[s][r] = (short)f2bf(p);
      }
    }
    psum += __shfl_xor(psum, 16);
    psum += __shfl_xor(psum, 32);
    lrun = lrun * corr + psum;

    float cr[4];
#pragma unroll
    for (int r = 0; r < 4; ++r) cr[r] = __shfl(corr, g * 4 + r);
#pragma unroll
    for (int dt = 0; dt < 16; ++dt)
#pragma unroll
      for (int r = 0; r < 4; ++r) o[dt][r] *= cr[r];

#pragma unroll
    for (int dt = 0; dt < 16; ++dt) {
      const int d = dt * 16 + lm;
      const int swz = (((d >> 4) ^ d) & 15) << 3;
#pragma unroll
      for (int s = 0; s < 4; ++s) {
        short4_ vf = *(const short4_*)&sVT[d * 128 + ((s * 32 + g * 8) ^ swz)];
        o[dt] = MFMA16(pk[s], vf, o[dt]);
      }
    }
    __syncthreads();
  }

  const float inv = 1.f / lrun;
  float ir[4];
#pragma unroll
  for (int r = 0; r < 4; ++r) ir[r] = __shfl(inv, g * 4 + r);
  float* op = Out + (bS + (size_t)(qb * 64 + w * 16)) * D_DIM;
#pragma unroll
  for (int dt = 0; dt < 16; ++dt)
#pragma unroll
    for (int r = 0; r < 4; ++r)
      op[(size_t)(g * 4 + r) * D_DIM + dt * 16 + lm] = o[dt][r] * ir[r];
}

extern "C" void kernel_launch(void* const* d_in, const int* in_sizes, int n_in,
                              void* d_out, int out_size, void* d_ws, size_t ws_size,
                              hipStream_t stream) {
  const float* x_q = (const float*)d_in[0];
  const float* x_k = (const float*)d_in[1];
  const float* x_v = (const float*)d_in[2];
  const int* amask = (const int*)d_in[3];
  const float* Wq = (const float*)d_in[4];
  const float* Wk = (const float*)d_in[5];
  const float* Wv = (const float*)d_in[6];

  unsigned short* Qb = (unsigned short*)d_ws;
  unsigned short* Kb = Qb + BSD_TOT;
  unsigned short* Vb = Kb + BSD_TOT;

  const size_t qkv_bytes = 3 * BSD_TOT * sizeof(unsigned short);   // 25.2 MB
  const size_t pall_bytes = 4 * BSD_TOT * sizeof(unsigned short);  // 33.6 MB
  const size_t stat_bytes = 8 * (size_t)BS_TOT * sizeof(float);    // 512 KB
  const size_t flag_bytes = (size_t)B_N * 64 * sizeof(int);        // 1 KB
  if (ws_size >= qkv_bytes + pall_bytes + stat_bytes + flag_bytes) {
    unsigned short* Pall = (unsigned short*)((char*)d_ws + qkv_bytes);
    float* stats = (float*)((char*)d_ws + qkv_bytes + pall_bytes);
    int* tflags = (int*)((char*)d_ws + qkv_bytes + pall_bytes + stat_bytes);
    proj_kernel<<<dim3(768), dim3(256), 0, stream>>>(x_q, x_k, x_v, Wq, Wk, Wv, Qb, Kb,
                                                     Vb, amask, tflags);
    attn_split4_kernel<<<dim3(256), dim3(512), 0, stream>>>(
        Qb, Kb, Vb, amask, tflags, Pall, stats);
    combine4_kernel<<<dim3((unsigned)(BSD_TOT / 4 / 256)), dim3(256), 0, stream>>>(
        (float*)d_out, Pall, stats);
  } else {
    proj_kernel<<<dim3(768), dim3(256), 0, stream>>>(x_q, x_k, x_v, Wq, Wk, Wv, Qb, Kb,
                                                     Vb, amask,
                                                     (int*)((char*)d_ws + qkv_bytes));
    attn_kernel<<<dim3(B_N * (S_LEN / 64)), dim3(256), 0, stream>>>(Qb, Kb, Vb, amask,
                                                                    (float*)d_out);
  }
}